// Round 11
// baseline (245.327 us; speedup 1.0000x reference)
//
#include <hip/hip_runtime.h>
#include <hip/hip_bf16.h>
#include <stdint.h>

// MHSA: B=2, T=2048, C=1024, H=16, d=64. fp32 in/out, bf16 MFMA, fp32 accum.
// Round 11: r10 post-mortem — the sV remap traded hidden LDS-write conflicts
// for exposed V global-load decoalescing (attn 76.5->81 despite conflicts
// -58%). Revert to r9 coalesced V mapping (svr=tid>>3: 8 lanes = one 128B
// row); fix write conflicts via row stride 72->68 elems (36->34 words mod 32:
// 4->2) => writer 16-way -> 8-way, reader b64 stays ~2-way, alignment OK.
// Keep: diagonal chunk-skip, r9 key-split, K3 NT=64, merged pre/post.

typedef __bf16 bf16_t;
typedef __bf16 bf16x8 __attribute__((ext_vector_type(8)));
typedef __bf16 bf16x4 __attribute__((ext_vector_type(4)));
typedef short  s16x4  __attribute__((ext_vector_type(4)));
typedef float  f32x4  __attribute__((ext_vector_type(4)));

#define SEQ   2048
#define DM    1024
#define NH    16
#define DH    64
#define BATCH 2
#define SVP   68   // sV row stride (elems): 34 words == 2 mod 32 banks

__device__ __forceinline__ bf16x8 load8(const bf16_t* p) {
    return *reinterpret_cast<const bf16x8*>(p);
}
__device__ __forceinline__ f32x4 loadf4(const float* p) {
    return *reinterpret_cast<const f32x4*>(p);
}
// async global->LDS, 16B per lane. LDS dest = wave-uniform base + lane*16.
__device__ __forceinline__ void async16(const bf16_t* g, bf16_t* lds_base) {
    __builtin_amdgcn_global_load_lds(
        (const __attribute__((address_space(1))) void*)g,
        (__attribute__((address_space(3))) void*)lds_base, 16, 0, 0);
}
__device__ __forceinline__ float fast_exp2(float x) {
#if __has_builtin(__builtin_amdgcn_exp2f)
    return __builtin_amdgcn_exp2f(x);
#else
    return __expf(x * 0.69314718056f);
#endif
}

// ---------------------------------------------------------------------------
// tcvt helper (device): transpose+convert one 64x64 tile of w [1024][N] fp32
// into wT [N][1024] bf16.
// ---------------------------------------------------------------------------
__device__ __forceinline__ void tcvt_tile(
    const float* __restrict__ w, bf16_t* __restrict__ wT, int N,
    int n0, int k0, bf16_t (*tile)[65])
{
    const int tid = threadIdx.x;
#pragma unroll
    for (int i = 0; i < 4; ++i) {
        const int r = i * 16 + (tid >> 4);      // k-local
        const int c = (tid & 15) * 4;           // n-local
        f32x4 v = loadf4(w + (size_t)(k0 + r) * N + n0 + c);
#pragma unroll
        for (int j = 0; j < 4; ++j) tile[c + j][r] = (bf16_t)v[j];
    }
    __syncthreads();
#pragma unroll
    for (int i = 0; i < 4; ++i) {
        const int r = i * 16 + (tid >> 4);      // n-local
        const int c = (tid & 15) * 4;           // k-local
        ushort4 v;
        v.x = *(const uint16_t*)&tile[r][c];
        v.y = *(const uint16_t*)&tile[r][c + 1];
        v.z = *(const uint16_t*)&tile[r][c + 2];
        v.w = *(const uint16_t*)&tile[r][c + 3];
        *reinterpret_cast<ushort4*>(wT + (size_t)(n0 + r) * DM + k0 + c) = v;
    }
}

// ---------------------------------------------------------------------------
// pre: blocks [0,2048): x fp32 -> xb bf16 (8 elems/thread);
//      blocks [2048,2816): tcvt tiles of w_qkv (48 x 16 tiles).
// ---------------------------------------------------------------------------
__global__ __launch_bounds__(256) void pre_kernel(
    const float* __restrict__ x, bf16_t* __restrict__ xb,
    const float* __restrict__ w_qkv, bf16_t* __restrict__ wqkvT)
{
    __shared__ bf16_t tile[64][65];
    const int bid = blockIdx.x;
    if (bid < 2048) {
        const int i = (bid * 256 + threadIdx.x) * 8;
        f32x4 a = loadf4(x + i);
        f32x4 b = loadf4(x + i + 4);
        bf16x8 v;
#pragma unroll
        for (int j = 0; j < 4; ++j) { v[j] = (bf16_t)a[j]; v[4 + j] = (bf16_t)b[j]; }
        *reinterpret_cast<bf16x8*>(xb + i) = v;
    } else {
        const int t = bid - 2048;                // 0..767
        tcvt_tile(w_qkv, wqkvT, 3072, (t % 48) * 64, (t / 48) * 64, tile);
    }
}

// standalone tcvt (small-ws path)
__global__ __launch_bounds__(256) void tcvt_kernel(
    const float* __restrict__ w, bf16_t* __restrict__ wT, int N)
{
    __shared__ bf16_t tile[64][65];
    tcvt_tile(w, wT, N, blockIdx.x * 64, blockIdx.y * 64, tile);
}

// ---------------------------------------------------------------------------
// 128xNT-tile bf16 GEMM, K=1024, BK=64. A [M,1024] row-major (TA = float:
// convert-in-staging; TA = bf16: global_load_lds). BT [N,1024] bf16.
// Block 256 = 4 waves (2x2): wave covers 64 x NT/2 (4 x NT/32 MFMA subtiles).
// MODE 0: scatter+bias into Q/K/V [B,H,T,64] bf16. MODE 1: fp32 out + bias.
// ---------------------------------------------------------------------------
template <typename TA, int MODE, int NT>
__global__ __launch_bounds__(256) void gemm_bt_kernel(
    const TA* __restrict__ A, const bf16_t* __restrict__ BT,
    const float* __restrict__ bias,
    float* __restrict__ outF,
    bf16_t* __restrict__ oq, bf16_t* __restrict__ ok, bf16_t* __restrict__ ov)
{
    constexpr int SAS = (sizeof(TA) == 4) ? 72 : 64;   // sA row stride (elems)
    constexpr int NB  = NT / 32;                       // b-subtiles per wave
    __shared__ bf16_t sA[128 * SAS];
    __shared__ bf16_t sB[NT * 64];

    const int tid  = threadIdx.x;
    const int lane = tid & 63;
    const int wv   = tid >> 6;
    const int lq   = lane >> 4;
    const int lm   = lane & 15;
    const int wm   = (wv >> 1) * 64;
    const int wn   = (wv & 1) * (NT / 2);
    const int mb   = blockIdx.y * 128;
    const int nb   = blockIdx.x * NT;

    const int srow = lane >> 3;          // 0..7
    const int scol = (lane & 7) * 8;     // elem offset (16B chunks)

    f32x4 acc[4][NB];
#pragma unroll
    for (int a = 0; a < 4; ++a)
#pragma unroll
        for (int b = 0; b < NB; ++b) acc[a][b] = f32x4{0.f, 0.f, 0.f, 0.f};

    for (int it = 0; it < 16; ++it) {
        const int k0 = it * 64;
        if constexpr (sizeof(TA) == 4) {
            const int arow = tid >> 1;
            const int akc  = (tid & 1) * 32;
            const float* g = (const float*)A + (size_t)(mb + arow) * DM + k0 + akc;
            bf16_t* dst = &sA[arow * SAS + akc];
#pragma unroll
            for (int j = 0; j < 4; ++j) {
                f32x4 u0 = loadf4(g + j * 8);
                f32x4 u1 = loadf4(g + j * 8 + 4);
                bf16x8 w;
#pragma unroll
                for (int e = 0; e < 4; ++e) { w[e] = (bf16_t)u0[e]; w[4 + e] = (bf16_t)u1[e]; }
                *reinterpret_cast<bf16x8*>(dst + j * 8) = w;
            }
        } else {
#pragma unroll
            for (int r = 0; r < 4; ++r) {
                const int row = wv * 32 + r * 8 + srow;
                async16((const bf16_t*)A + (size_t)(mb + row) * DM + k0 + scol,
                        &sA[wv * 2048 + r * 512]);
            }
        }
#pragma unroll
        for (int r = 0; r < NT / 32; ++r) {
            const int row = wv * (NT / 4) + r * 8 + srow;
            async16(BT + (size_t)(nb + row) * DM + k0 + scol,
                    &sB[wv * (NT / 4) * 64 + r * 512]);
        }
        __syncthreads();
#pragma unroll
        for (int kh = 0; kh < 2; ++kh) {
            bf16x8 af[4], bfr[NB];
#pragma unroll
            for (int a = 0; a < 4; ++a)
                af[a] = load8(&sA[(wm + a * 16 + lm) * SAS + kh * 32 + lq * 8]);
#pragma unroll
            for (int b = 0; b < NB; ++b)
                bfr[b] = load8(&sB[(wn + b * 16 + lm) * 64 + kh * 32 + lq * 8]);
#pragma unroll
            for (int a = 0; a < 4; ++a)
#pragma unroll
                for (int b = 0; b < NB; ++b)
                    acc[a][b] = __builtin_amdgcn_mfma_f32_16x16x32_bf16(
                        af[a], bfr[b], acc[a][b], 0, 0, 0);
        }
        __syncthreads();
    }

    // epilogue: C/D layout col = lane&15, row = (lane>>4)*4 + r
#pragma unroll
    for (int b = 0; b < NB; ++b) {
        const int n = nb + wn + b * 16 + lm;
        const float bv = bias[n];
        if (MODE == 0) {
            const int which = n >> 10;
            const int cc = n & 1023;
            const int h  = cc >> 6;
            const int d  = cc & 63;
            bf16_t* dst = (which == 0) ? oq : (which == 1) ? ok : ov;
#pragma unroll
            for (int a = 0; a < 4; ++a)
#pragma unroll
                for (int r = 0; r < 4; ++r) {
                    const int m = mb + wm + a * 16 + lq * 4 + r;
                    const int bb = m >> 11;
                    const int t  = m & 2047;
                    dst[((size_t)(bb * NH + h) * SEQ + t) * DH + d] =
                        (bf16_t)(acc[a][b][r] + bv);
                }
        } else {
#pragma unroll
            for (int a = 0; a < 4; ++a)
#pragma unroll
                for (int r = 0; r < 4; ++r) {
                    const int m = mb + wm + a * 16 + lq * 4 + r;
                    outF[(size_t)m * DM + n] = acc[a][b][r] + bv;
                }
        }
    }
}

// ---------------------------------------------------------------------------
// Flash attention, S^T formulation, 128-row q-tiles, r9 key-split.
// split=0: grid.x=16, qi=15-uid, full range. split=1: grid.x=24 (r9 map).
// V stage: svr=tid>>3 (coalesced 128B global rows), sV stride 68 elems
// (writer 8-way banks vs 72's 16-way). Diagonal chunk skip kept.
// ---------------------------------------------------------------------------
__global__ __launch_bounds__(256) void attn_kernel(
    const bf16_t* __restrict__ qbuf, const bf16_t* __restrict__ kbuf,
    const bf16_t* __restrict__ vbuf, bf16_t* __restrict__ ybuf,
    bf16_t* __restrict__ p1, float* __restrict__ l0buf,
    float* __restrict__ l1buf, int split)
{
    __shared__ bf16_t sK[2][64 * 64];                // [key][d], contiguous
    __shared__ __align__(16) bf16_t sV[2][64][SVP];  // [d][key], stride 68

    const int tid  = threadIdx.x;
    const int lane = tid & 63;
    const int wv   = tid >> 6;
    const int lq   = lane >> 4;
    const int lm   = lane & 15;
    const int uid  = blockIdx.x;
    const int bh   = blockIdx.y;

    int qi, kt0, ktn, chunk1;
    if (!split)        { qi = 15 - uid;        kt0 = 0;  ktn = 2 * qi + 2;      chunk1 = 0; }
    else if (uid < 9)  { qi = 15 - uid;        kt0 = 0;  ktn = 16;              chunk1 = 0; }
    else if (uid < 17) { qi = 15 - (uid - 9);  kt0 = 16; ktn = 2 * qi + 2 - 16; chunk1 = 1; }
    else               { qi = 6 - (uid - 17);  kt0 = 0;  ktn = 2 * qi + 2;      chunk1 = 0; }
    const bool fin = !split || (!chunk1 && qi < 8);
    const int q_base = qi * 128;

    const size_t hb = (size_t)bh * SEQ * DH;
    const bf16_t* Q = qbuf + hb;
    const bf16_t* K = kbuf + hb;
    const bf16_t* V = vbuf + hb;

    // Q fragments (B-operand of K.Q^T): lane lm = query, k = lq*8+j over d
    bf16x8 qf0[2], qf1[2];
#pragma unroll
    for (int ms = 0; ms < 2; ++ms) {
        const bf16_t* p = Q + (size_t)(q_base + wv * 32 + ms * 16 + lm) * DH + lq * 8;
        qf0[ms] = load8(p);
        qf1[ms] = load8(p + 32);
    }

    f32x4 o[2][4];                     // O^T: [ms][d-subtile], d=lq*4+r, q=lm
    float ls[2];                       // lane-local row-sum (query = lm)
#pragma unroll
    for (int ms = 0; ms < 2; ++ms) {
        ls[ms] = 0.f;
#pragma unroll
        for (int dc = 0; dc < 4; ++dc) o[ms][dc] = f32x4{0.f, 0.f, 0.f, 0.f};
    }

    const int krow = lane >> 3;          // K-stage row sub
    const int kcol8 = (lane & 7) * 8;    // K-stage col elems
    const int svr = tid >> 3;            // V-stage key row (8 lanes = 128B row)
    const int svd = (tid & 7) * 8;       // V-stage d offset

    // prologue: stage tile kt0
    {
        const int kb0 = kt0 * 64;
#pragma unroll
        for (int r = 0; r < 2; ++r)
            async16(K + (size_t)(kb0 + wv * 16 + r * 8 + krow) * DH + kcol8,
                    &sK[0][wv * 1024 + r * 512]);
        bf16x8 va = load8(V + (size_t)(kb0 + svr) * DH + svd);
        bf16x8 vb = load8(V + (size_t)(kb0 + 32 + svr) * DH + svd);
#pragma unroll
        for (int j = 0; j < 8; ++j) { sV[0][svd + j][svr] = va[j]; sV[0][svd + j][32 + svr] = vb[j]; }
    }
    __syncthreads();

    const float c1 = 0.125f * 1.44269504f;   // scale * log2(e)
    const float c2 = 10.0f  * 1.44269504f;   // fixed shift * log2(e)

    for (int st = 0; st < ktn; ++st) {
        const int kt = kt0 + st;
        const int cb = st & 1, nbuf = cb ^ 1;
        const int kb = kt * 64;
        const bool pre = (st + 1 < ktn);
        bf16x8 vpa, vpb;
        if (pre) {
            const int kb2 = kb + 64;
#pragma unroll
            for (int r = 0; r < 2; ++r)
                async16(K + (size_t)(kb2 + wv * 16 + r * 8 + krow) * DH + kcol8,
                        &sK[nbuf][wv * 1024 + r * 512]);
            vpa = load8(V + (size_t)(kb2 + svr) * DH + svd);
            vpb = load8(V + (size_t)(kb2 + 32 + svr) * DH + svd);
        }

        // K fragments (A-operand): lane lm = key, k = lq*8+j over d
        const bf16_t* sKc = sK[cb];
        bf16x8 kf0[4], kf1[4];
#pragma unroll
        for (int c = 0; c < 4; ++c) {
            const bf16_t* p = &sKc[(c * 16 + lm) * 64 + lq * 8];
            kf0[c] = load8(p);
            kf1[c] = load8(p + 32);
        }
        // V A-frags for PV-K16: A[m=d: dc*16+lm][k=key: c*16+lq*4+j] (b64)
        s16x4 vf[4][4];
#pragma unroll
        for (int dc = 0; dc < 4; ++dc)
#pragma unroll
            for (int c = 0; c < 4; ++c)
                vf[dc][c] = *reinterpret_cast<const s16x4*>(
                    &sV[cb][dc * 16 + lm][c * 16 + lq * 4]);

#pragma unroll
        for (int ms = 0; ms < 2; ++ms) {
            const int rowlo = wv * 32 + ms * 16;              // block-relative
            if (q_base + rowlo + 15 < kb) continue;           // fully masked

            const bool diag = (kb + 63 > q_base + rowlo);
            int cmax = 3;
            if (diag) {
                const int cm = (q_base + rowlo + 15 - kb) >> 4;
                cmax = (cm < 3) ? cm : 3;
            }

            // S^T: C[m=key: lq*4+r][n=query: lm]
            f32x4 s[4];
#pragma unroll
            for (int c = 0; c < 4; ++c) {
                if (c > cmax) continue;
                f32x4 z = f32x4{0.f, 0.f, 0.f, 0.f};
                f32x4 t0 = __builtin_amdgcn_mfma_f32_16x16x32_bf16(kf0[c], qf0[ms], z, 0, 0, 0);
                s[c] = __builtin_amdgcn_mfma_f32_16x16x32_bf16(kf1[c], qf1[ms], t0, 0, 0, 0);
            }

            const int q = q_base + rowlo + lm;    // this lane's query
            float p4[4][4];
            if (diag) {
#pragma unroll
                for (int c = 0; c < 4; ++c) {
                    if (c > cmax) continue;
#pragma unroll
                    for (int r = 0; r < 4; ++r) {
                        const int key = kb + c * 16 + lq * 4 + r;
                        float t = (key <= q) ? fmaf(s[c][r], c1, -c2) : -1e30f;
                        p4[c][r] = fast_exp2(t);
                    }
                }
            } else {
#pragma unroll
                for (int c = 0; c < 4; ++c)
#pragma unroll
                    for (int r = 0; r < 4; ++r)
                        p4[c][r] = fast_exp2(fmaf(s[c][r], c1, -c2));
            }
            float lsum = 0.f;
#pragma unroll
            for (int c = 0; c < 4; ++c) {
                if (c > cmax) continue;
                lsum += (p4[c][0] + p4[c][1]) + (p4[c][2] + p4[c][3]);
            }
            ls[ms] += lsum;

            // P -> bf16 B-frags (already in B-operand layout for K16 MFMA)
            s16x4 pf[4];
#pragma unroll
            for (int c = 0; c < 4; ++c) {
                if (c > cmax) continue;
                bf16x4 v;
#pragma unroll
                for (int r = 0; r < 4; ++r) v[r] = (bf16_t)p4[c][r];
                pf[c] = __builtin_bit_cast(s16x4, v);
            }

            // O^T += V^T . P   (16x16x16, K=16 per key-chunk c)
#pragma unroll
            for (int dc = 0; dc < 4; ++dc)
#pragma unroll
                for (int c = 0; c < 4; ++c) {
                    if (c > cmax) continue;
                    o[ms][dc] = __builtin_amdgcn_mfma_f32_16x16x16bf16_1k(
                        vf[dc][c], pf[c], o[ms][dc], 0, 0, 0);
                }
        }

        if (pre) {
#pragma unroll
            for (int j = 0; j < 8; ++j) { sV[nbuf][svd + j][svr] = vpa[j]; sV[nbuf][svd + j][32 + svr] = vpb[j]; }
        }
        __syncthreads();
    }

    // epilogue: reduce row-sum over lq groups, normalize if finalizing,
    // transpose O^T -> row-major via LDS scratch (reuse sK), coalesced stores.
    __syncthreads();                       // all waves done with sK/sV reads
    bf16_t* sT = &sK[0][0];                // [wave][16 q][72] scratch
    const int b = bh >> 4;
    const int h = bh & 15;
#pragma unroll
    for (int ms = 0; ms < 2; ++ms) {
        float l = ls[ms];
        l += __shfl_xor(l, 16);
        l += __shfl_xor(l, 32);
        const float inv = fin ? (1.0f / l) : 1.0f;
        if (!fin && lq == 0) {             // lanes 0..15 write this ms's l
            const int q = q_base + wv * 32 + ms * 16 + lm;
            float* lb = chunk1 ? l1buf : l0buf;
            lb[bh * 1024 + (q - 1024)] = l;
        }
#pragma unroll
        for (int dc = 0; dc < 4; ++dc)
#pragma unroll
            for (int r = 0; r < 4; ++r)
                sT[wv * 1152 + lm * 72 + dc * 16 + lq * 4 + r] =
                    (bf16_t)(o[ms][dc][r] * inv);
        // within-wave transpose readback: lane -> (q = lane&15, d-half = lane>>4)
        const int t = q_base + wv * 32 + ms * 16 + (lane & 15);
        const bf16_t* src = &sT[wv * 1152 + (lane & 15) * 72 + (lane >> 4) * 16];
        bf16x8 y0 = load8(src);
        bf16x8 y1 = load8(src + 8);
        bf16_t* dst;
        if (chunk1)
            dst = p1 + ((size_t)(bh * 1024 + (t - 1024))) * 64 + (lane >> 4) * 16;
        else
            dst = ybuf + ((size_t)(b * SEQ + t)) * DM + h * DH + (lane >> 4) * 16;
        *reinterpret_cast<bf16x8*>(dst)     = y0;
        *reinterpret_cast<bf16x8*>(dst + 8) = y1;
    }
}

// ---------------------------------------------------------------------------
// post: blocks [0,1024): combine q>=1024 rows: y = (O0+O1)/(l0+l1);
//       blocks [1024,1280): tcvt tiles of w_out -> woutT (16 x 16 tiles).
// ---------------------------------------------------------------------------
__global__ __launch_bounds__(256) void post_kernel(
    bf16_t* __restrict__ yb, const bf16_t* __restrict__ p1,
    const float* __restrict__ l0, const float* __restrict__ l1,
    const float* __restrict__ w_out, bf16_t* __restrict__ woutT)
{
    __shared__ bf16_t tile[64][65];
    const int bid = blockIdx.x;
    if (bid < 1024) {
        const int idx = bid * 256 + threadIdx.x;
        const int d8  = (idx & 7) * 8;
        const int row = idx >> 3;              // bh*1024 + (q-1024)
        const int ql  = row & 1023;
        const int bh  = row >> 10;
        const int q   = 1024 + ql;
        const int b   = bh >> 4, h = bh & 15;
        const float inv = 1.0f / (l0[row] + l1[row]);
        bf16_t* yp = yb + ((size_t)(b * SEQ + q)) * DM + h * DH + d8;
        const bf16_t* pp = p1 + (size_t)row * 64 + d8;
        bf16x8 a = load8(yp), c = load8(pp);
        bf16x8 oo;
#pragma unroll
        for (int j = 0; j < 8; ++j)
            oo[j] = (bf16_t)(((float)a[j] + (float)c[j]) * inv);
        *reinterpret_cast<bf16x8*>(yp) = oo;
    } else {
        const int t = bid - 1024;              // 0..255
        tcvt_tile(w_out, woutT, 1024, (t % 16) * 64, (t / 16) * 64, tile);
    }
}

// ---------------------------------------------------------------------------
extern "C" void kernel_launch(void* const* d_in, const int* in_sizes, int n_in,
                              void* d_out, int out_size, void* d_ws, size_t ws_size,
                              hipStream_t stream)
{
    const float* x     = (const float*)d_in[0];
    const float* w_qkv = (const float*)d_in[1];
    const float* b_qkv = (const float*)d_in[2];
    const float* w_out = (const float*)d_in[3];
    const float* b_out = (const float*)d_in[4];
    float* out = (float*)d_out;

    char* ws = (char*)d_ws;
    bf16_t* qb = (bf16_t*)(ws);                 // 0..8M
    bf16_t* kb = (bf16_t*)(ws + (8u << 20));    // 8..16M
    bf16_t* vb = (bf16_t*)(ws + (16u << 20));   // 16..24M
    bf16_t* yb = (bf16_t*)(ws + (24u << 20));   // 24..32M
    bf16_t* woutT = qb;   // 2 MB; written after attention (qb dead by then)

    const bool bigws = (ws_size >= ((size_t)38 << 20));

    if (bigws) {
        bf16_t* xb    = yb;                                // dead before attn-Y
        bf16_t* wqkvT = (bf16_t*)(ws + (32u << 20));       // 32..38M (dead after K1)
        pre_kernel<<<dim3(2048 + 768), dim3(256), 0, stream>>>(x, xb, w_qkv, wqkvT);
        gemm_bt_kernel<bf16_t, 0, 128><<<dim3(3072 / 128, 4096 / 128), dim3(256), 0, stream>>>(
            xb, wqkvT, b_qkv, nullptr, qb, kb, vb);

        bf16_t* p1 = (bf16_t*)(ws + (32u << 20));              // 4 MB partials
        float*  l0 = (float*)(ws + (36u << 20));               // 128 KB
        float*  l1 = (float*)(ws + (36u << 20) + (128u << 10));// 128 KB
        attn_kernel<<<dim3(24, BATCH * NH), dim3(256), 0, stream>>>(
            qb, kb, vb, yb, p1, l0, l1, 1);
        post_kernel<<<dim3(1024 + 256), dim3(256), 0, stream>>>(
            yb, p1, l0, l1, w_out, woutT);
    } else {
        bf16_t* wqkvT = yb;
        tcvt_kernel<<<dim3(3072 / 64, 1024 / 64), dim3(256), 0, stream>>>(w_qkv, wqkvT, 3072);
        gemm_bt_kernel<float, 0, 128><<<dim3(3072 / 128, 4096 / 128), dim3(256), 0, stream>>>(
            x, wqkvT, b_qkv, nullptr, qb, kb, vb);
        attn_kernel<<<dim3(16, BATCH * NH), dim3(256), 0, stream>>>(
            qb, kb, vb, yb, yb, nullptr, nullptr, 0);
        tcvt_kernel<<<dim3(1024 / 64, 1024 / 64), dim3(256), 0, stream>>>(w_out, woutT, 1024);
    }

    // K3: output projection, 128x64 tiles (512 blocks, 2/CU) -> d_out fp32
    gemm_bt_kernel<bf16_t, 1, 64><<<dim3(1024 / 64, 4096 / 128), dim3(256), 0, stream>>>(
        yb, woutT, b_out, out, nullptr, nullptr, nullptr);
}

// Round 12
// 232.983 us; speedup vs baseline: 1.0530x; 1.0530x over previous
//
#include <hip/hip_runtime.h>
#include <hip/hip_bf16.h>
#include <stdint.h>

// MHSA: B=2, T=2048, C=1024, H=16, d=64. fp32 in/out, bf16 MFMA, fp32 accum.
// Round 12: (a) chunk-skip REVERTED (r10/r11 post-mortem: it — not the sV
// mapping — cost 4.5us; conflicts halved with zero time effect, so the
// branches broke the MFMA pipeline). (b) V transposed in GLOBAL by K1's
// epilogue (VT[b,h,d,t]; 8B stores, 4 consecutive t per acc column); attn
// stages V via async16 like K — per-tile 16 global loads + 16 scalar LDS
// writes + reg prefetch deleted. (c) XOR swizzle on async16 sources for both
// sK and sVt: logical chunk c at physical c^(row&7) -> kf b128 reads 16-way
// -> 2-way, vf b64 reads 4-way. Keep: r9 key-split, K3 NT=64, merged pre/post.

typedef __bf16 bf16_t;
typedef __bf16 bf16x8 __attribute__((ext_vector_type(8)));
typedef __bf16 bf16x4 __attribute__((ext_vector_type(4)));
typedef short  s16x4  __attribute__((ext_vector_type(4)));
typedef float  f32x4  __attribute__((ext_vector_type(4)));

#define SEQ   2048
#define DM    1024
#define NH    16
#define DH    64
#define BATCH 2

__device__ __forceinline__ bf16x8 load8(const bf16_t* p) {
    return *reinterpret_cast<const bf16x8*>(p);
}
__device__ __forceinline__ f32x4 loadf4(const float* p) {
    return *reinterpret_cast<const f32x4*>(p);
}
// async global->LDS, 16B per lane. LDS dest = wave-uniform base + lane*16.
__device__ __forceinline__ void async16(const bf16_t* g, bf16_t* lds_base) {
    __builtin_amdgcn_global_load_lds(
        (const __attribute__((address_space(1))) void*)g,
        (__attribute__((address_space(3))) void*)lds_base, 16, 0, 0);
}
__device__ __forceinline__ float fast_exp2(float x) {
#if __has_builtin(__builtin_amdgcn_exp2f)
    return __builtin_amdgcn_exp2f(x);
#else
    return __expf(x * 0.69314718056f);
#endif
}
// swizzled 64x64 bf16 LDS tile: logical (row, chunk8) at physical chunk8^(row&7)
__device__ __forceinline__ int swz(int row, int chunk) {
    return row * 64 + ((chunk ^ (row & 7)) * 8);
}

// ---------------------------------------------------------------------------
// tcvt helper (device): transpose+convert one 64x64 tile of w [1024][N] fp32
// into wT [N][1024] bf16.
// ---------------------------------------------------------------------------
__device__ __forceinline__ void tcvt_tile(
    const float* __restrict__ w, bf16_t* __restrict__ wT, int N,
    int n0, int k0, bf16_t (*tile)[65])
{
    const int tid = threadIdx.x;
#pragma unroll
    for (int i = 0; i < 4; ++i) {
        const int r = i * 16 + (tid >> 4);      // k-local
        const int c = (tid & 15) * 4;           // n-local
        f32x4 v = loadf4(w + (size_t)(k0 + r) * N + n0 + c);
#pragma unroll
        for (int j = 0; j < 4; ++j) tile[c + j][r] = (bf16_t)v[j];
    }
    __syncthreads();
#pragma unroll
    for (int i = 0; i < 4; ++i) {
        const int r = i * 16 + (tid >> 4);      // n-local
        const int c = (tid & 15) * 4;           // k-local
        ushort4 v;
        v.x = *(const uint16_t*)&tile[r][c];
        v.y = *(const uint16_t*)&tile[r][c + 1];
        v.z = *(const uint16_t*)&tile[r][c + 2];
        v.w = *(const uint16_t*)&tile[r][c + 3];
        *reinterpret_cast<ushort4*>(wT + (size_t)(n0 + r) * DM + k0 + c) = v;
    }
}

// ---------------------------------------------------------------------------
// pre: blocks [0,2048): x fp32 -> xb bf16 (8 elems/thread);
//      blocks [2048,2816): tcvt tiles of w_qkv (48 x 16 tiles).
// ---------------------------------------------------------------------------
__global__ __launch_bounds__(256) void pre_kernel(
    const float* __restrict__ x, bf16_t* __restrict__ xb,
    const float* __restrict__ w_qkv, bf16_t* __restrict__ wqkvT)
{
    __shared__ bf16_t tile[64][65];
    const int bid = blockIdx.x;
    if (bid < 2048) {
        const int i = (bid * 256 + threadIdx.x) * 8;
        f32x4 a = loadf4(x + i);
        f32x4 b = loadf4(x + i + 4);
        bf16x8 v;
#pragma unroll
        for (int j = 0; j < 4; ++j) { v[j] = (bf16_t)a[j]; v[4 + j] = (bf16_t)b[j]; }
        *reinterpret_cast<bf16x8*>(xb + i) = v;
    } else {
        const int t = bid - 2048;                // 0..767
        tcvt_tile(w_qkv, wqkvT, 3072, (t % 48) * 64, (t / 48) * 64, tile);
    }
}

// standalone tcvt (small-ws path)
__global__ __launch_bounds__(256) void tcvt_kernel(
    const float* __restrict__ w, bf16_t* __restrict__ wT, int N)
{
    __shared__ bf16_t tile[64][65];
    tcvt_tile(w, wT, N, blockIdx.x * 64, blockIdx.y * 64, tile);
}

// ---------------------------------------------------------------------------
// 128xNT-tile bf16 GEMM, K=1024, BK=64. A [M,1024] row-major (TA = float:
// convert-in-staging; TA = bf16: global_load_lds). BT [N,1024] bf16.
// Block 256 = 4 waves (2x2): wave covers 64 x NT/2 (4 x NT/32 MFMA subtiles).
// MODE 0: Q,K scattered to [B,H,T,64]; V scattered TRANSPOSED to [B,H,64,T]
// (8B stores: 4 consecutive t). MODE 1: fp32 out + bias.
// ---------------------------------------------------------------------------
template <typename TA, int MODE, int NT>
__global__ __launch_bounds__(256) void gemm_bt_kernel(
    const TA* __restrict__ A, const bf16_t* __restrict__ BT,
    const float* __restrict__ bias,
    float* __restrict__ outF,
    bf16_t* __restrict__ oq, bf16_t* __restrict__ ok, bf16_t* __restrict__ ov)
{
    constexpr int SAS = (sizeof(TA) == 4) ? 72 : 64;   // sA row stride (elems)
    constexpr int NB  = NT / 32;                       // b-subtiles per wave
    __shared__ bf16_t sA[128 * SAS];
    __shared__ bf16_t sB[NT * 64];

    const int tid  = threadIdx.x;
    const int lane = tid & 63;
    const int wv   = tid >> 6;
    const int lq   = lane >> 4;
    const int lm   = lane & 15;
    const int wm   = (wv >> 1) * 64;
    const int wn   = (wv & 1) * (NT / 2);
    const int mb   = blockIdx.y * 128;
    const int nb   = blockIdx.x * NT;

    const int srow = lane >> 3;          // 0..7
    const int scol = (lane & 7) * 8;     // elem offset (16B chunks)

    f32x4 acc[4][NB];
#pragma unroll
    for (int a = 0; a < 4; ++a)
#pragma unroll
        for (int b = 0; b < NB; ++b) acc[a][b] = f32x4{0.f, 0.f, 0.f, 0.f};

    for (int it = 0; it < 16; ++it) {
        const int k0 = it * 64;
        if constexpr (sizeof(TA) == 4) {
            const int arow = tid >> 1;
            const int akc  = (tid & 1) * 32;
            const float* g = (const float*)A + (size_t)(mb + arow) * DM + k0 + akc;
            bf16_t* dst = &sA[arow * SAS + akc];
#pragma unroll
            for (int j = 0; j < 4; ++j) {
                f32x4 u0 = loadf4(g + j * 8);
                f32x4 u1 = loadf4(g + j * 8 + 4);
                bf16x8 w;
#pragma unroll
                for (int e = 0; e < 4; ++e) { w[e] = (bf16_t)u0[e]; w[4 + e] = (bf16_t)u1[e]; }
                *reinterpret_cast<bf16x8*>(dst + j * 8) = w;
            }
        } else {
#pragma unroll
            for (int r = 0; r < 4; ++r) {
                const int row = wv * 32 + r * 8 + srow;
                async16((const bf16_t*)A + (size_t)(mb + row) * DM + k0 + scol,
                        &sA[wv * 2048 + r * 512]);
            }
        }
#pragma unroll
        for (int r = 0; r < NT / 32; ++r) {
            const int row = wv * (NT / 4) + r * 8 + srow;
            async16(BT + (size_t)(nb + row) * DM + k0 + scol,
                    &sB[wv * (NT / 4) * 64 + r * 512]);
        }
        __syncthreads();
#pragma unroll
        for (int kh = 0; kh < 2; ++kh) {
            bf16x8 af[4], bfr[NB];
#pragma unroll
            for (int a = 0; a < 4; ++a)
                af[a] = load8(&sA[(wm + a * 16 + lm) * SAS + kh * 32 + lq * 8]);
#pragma unroll
            for (int b = 0; b < NB; ++b)
                bfr[b] = load8(&sB[(wn + b * 16 + lm) * 64 + kh * 32 + lq * 8]);
#pragma unroll
            for (int a = 0; a < 4; ++a)
#pragma unroll
                for (int b = 0; b < NB; ++b)
                    acc[a][b] = __builtin_amdgcn_mfma_f32_16x16x32_bf16(
                        af[a], bfr[b], acc[a][b], 0, 0, 0);
        }
        __syncthreads();
    }

    // epilogue: C/D layout col = lane&15, row = (lane>>4)*4 + r
#pragma unroll
    for (int b = 0; b < NB; ++b) {
        const int n = nb + wn + b * 16 + lm;
        const float bv = bias[n];
        if (MODE == 0) {
            const int which = n >> 10;
            const int cc = n & 1023;
            const int h  = cc >> 6;
            const int d  = cc & 63;
            if (which == 2) {
                // V -> VT[b,h,d,t]: 4 consecutive t per acc column, 8B store
#pragma unroll
                for (int a = 0; a < 4; ++a) {
                    const int m0 = mb + wm + a * 16 + lq * 4;
                    const int bb = m0 >> 11;
                    const int t0 = m0 & 2047;
                    bf16x4 w;
#pragma unroll
                    for (int r = 0; r < 4; ++r) w[r] = (bf16_t)(acc[a][b][r] + bv);
                    *reinterpret_cast<bf16x4*>(
                        ov + ((size_t)(bb * NH + h) * DH + d) * SEQ + t0) = w;
                }
            } else {
                bf16_t* dst = (which == 0) ? oq : ok;
#pragma unroll
                for (int a = 0; a < 4; ++a)
#pragma unroll
                    for (int r = 0; r < 4; ++r) {
                        const int m = mb + wm + a * 16 + lq * 4 + r;
                        const int bb = m >> 11;
                        const int t  = m & 2047;
                        dst[((size_t)(bb * NH + h) * SEQ + t) * DH + d] =
                            (bf16_t)(acc[a][b][r] + bv);
                    }
            }
        } else {
#pragma unroll
            for (int a = 0; a < 4; ++a)
#pragma unroll
                for (int r = 0; r < 4; ++r) {
                    const int m = mb + wm + a * 16 + lq * 4 + r;
                    outF[(size_t)m * DM + n] = acc[a][b][r] + bv;
                }
        }
    }
}

// ---------------------------------------------------------------------------
// Flash attention, S^T formulation, 128-row q-tiles, r9 key-split.
// split=0: grid.x=16, qi=15-uid, full range. split=1: grid.x=24 (r9 map).
// K AND V (pre-transposed VT[b,h,d,t]) staged via async16, double-buffered,
// XOR-swizzled (logical chunk c at physical c^(row&7)): kf b128 reads 2-way,
// vf b64 reads 4-way. No register V prefetch, no scalar LDS writes, no
// chunk-skip (r10/r11 regression).
// ---------------------------------------------------------------------------
__global__ __launch_bounds__(256) void attn_kernel(
    const bf16_t* __restrict__ qbuf, const bf16_t* __restrict__ kbuf,
    const bf16_t* __restrict__ vtbuf, bf16_t* __restrict__ ybuf,
    bf16_t* __restrict__ p1, float* __restrict__ l0buf,
    float* __restrict__ l1buf, int split)
{
    __shared__ bf16_t sK[2][64 * 64];    // [key][d], swizzled
    __shared__ bf16_t sVt[2][64 * 64];   // [d][key], swizzled

    const int tid  = threadIdx.x;
    const int lane = tid & 63;
    const int wv   = tid >> 6;
    const int lq   = lane >> 4;
    const int lm   = lane & 15;
    const int uid  = blockIdx.x;
    const int bh   = blockIdx.y;

    int qi, kt0, ktn, chunk1;
    if (!split)        { qi = 15 - uid;        kt0 = 0;  ktn = 2 * qi + 2;      chunk1 = 0; }
    else if (uid < 9)  { qi = 15 - uid;        kt0 = 0;  ktn = 16;              chunk1 = 0; }
    else if (uid < 17) { qi = 15 - (uid - 9);  kt0 = 16; ktn = 2 * qi + 2 - 16; chunk1 = 1; }
    else               { qi = 6 - (uid - 17);  kt0 = 0;  ktn = 2 * qi + 2;      chunk1 = 0; }
    const bool fin = !split || (!chunk1 && qi < 8);
    const int q_base = qi * 128;

    const size_t hb = (size_t)bh * SEQ * DH;
    const bf16_t* Q  = qbuf + hb;
    const bf16_t* K  = kbuf + hb;
    const bf16_t* VT = vtbuf + hb;       // [d][t] rows of length SEQ

    // Q fragments (B-operand of K.Q^T): lane lm = query, k = lq*8+j over d
    bf16x8 qf0[2], qf1[2];
#pragma unroll
    for (int ms = 0; ms < 2; ++ms) {
        const bf16_t* p = Q + (size_t)(q_base + wv * 32 + ms * 16 + lm) * DH + lq * 8;
        qf0[ms] = load8(p);
        qf1[ms] = load8(p + 32);
    }

    f32x4 o[2][4];                     // O^T: [ms][d-subtile], d=lq*4+r, q=lm
    float ls[2];                       // lane-local row-sum (query = lm)
#pragma unroll
    for (int ms = 0; ms < 2; ++ms) {
        ls[ms] = 0.f;
#pragma unroll
        for (int dc = 0; dc < 4; ++dc) o[ms][dc] = f32x4{0.f, 0.f, 0.f, 0.f};
    }

    const int srow = lane >> 3;                    // staging row sub 0..7
    const int scs  = ((lane & 7) ^ srow) * 8;      // swizzled source chunk
    const int m7   = lm & 7;

    // prologue: stage tile kt0 (K and VT)
    {
        const int kb0 = kt0 * 64;
#pragma unroll
        for (int r = 0; r < 2; ++r) {
            async16(K + (size_t)(kb0 + wv * 16 + r * 8 + srow) * DH + scs,
                    &sK[0][wv * 1024 + r * 512]);
            async16(VT + (size_t)(wv * 16 + r * 8 + srow) * SEQ + kb0 + scs,
                    &sVt[0][wv * 1024 + r * 512]);
        }
    }
    __syncthreads();

    const float c1 = 0.125f * 1.44269504f;   // scale * log2(e)
    const float c2 = 10.0f  * 1.44269504f;   // fixed shift * log2(e)

    for (int st = 0; st < ktn; ++st) {
        const int kt = kt0 + st;
        const int cb = st & 1, nbuf = cb ^ 1;
        const int kb = kt * 64;
        if (st + 1 < ktn) {
            const int kb2 = kb + 64;
#pragma unroll
            for (int r = 0; r < 2; ++r) {
                async16(K + (size_t)(kb2 + wv * 16 + r * 8 + srow) * DH + scs,
                        &sK[nbuf][wv * 1024 + r * 512]);
                async16(VT + (size_t)(wv * 16 + r * 8 + srow) * SEQ + kb2 + scs,
                        &sVt[nbuf][wv * 1024 + r * 512]);
            }
        }

        // K fragments (A-operand): lane lm = key, k over d; swizzled chunks
        const bf16_t* sKc = sK[cb];
        const bf16_t* sVc = sVt[cb];
        bf16x8 kf0[4], kf1[4];
#pragma unroll
        for (int c = 0; c < 4; ++c) {
            kf0[c] = load8(&sKc[swz(c * 16 + lm, lq)]);
            kf1[c] = load8(&sKc[swz(c * 16 + lm, lq + 4)]);
        }
        // V A-frags: A[m=d: dc*16+lm][k=key: c*16+lq*4+j] (b64, swizzled)
        s16x4 vf[4][4];
#pragma unroll
        for (int dc = 0; dc < 4; ++dc)
#pragma unroll
            for (int c = 0; c < 4; ++c)
                vf[dc][c] = *reinterpret_cast<const s16x4*>(
                    &sVc[swz(dc * 16 + lm, c * 2 + (lq >> 1)) + (lq & 1) * 4]);

#pragma unroll
        for (int ms = 0; ms < 2; ++ms) {
            const int rowlo = wv * 32 + ms * 16;              // block-relative
            if (q_base + rowlo + 15 < kb) continue;           // fully masked

            // S^T: C[m=key: lq*4+r][n=query: lm]
            f32x4 s[4];
#pragma unroll
            for (int c = 0; c < 4; ++c) {
                f32x4 z = f32x4{0.f, 0.f, 0.f, 0.f};
                f32x4 t0 = __builtin_amdgcn_mfma_f32_16x16x32_bf16(kf0[c], qf0[ms], z, 0, 0, 0);
                s[c] = __builtin_amdgcn_mfma_f32_16x16x32_bf16(kf1[c], qf1[ms], t0, 0, 0, 0);
            }

            const int q = q_base + rowlo + lm;    // this lane's query
            float p4[4][4];
            if (kb + 63 > q_base + rowlo) {       // diagonal region
#pragma unroll
                for (int c = 0; c < 4; ++c)
#pragma unroll
                    for (int r = 0; r < 4; ++r) {
                        const int key = kb + c * 16 + lq * 4 + r;
                        float t = (key <= q) ? fmaf(s[c][r], c1, -c2) : -1e30f;
                        p4[c][r] = fast_exp2(t);
                    }
            } else {
#pragma unroll
                for (int c = 0; c < 4; ++c)
#pragma unroll
                    for (int r = 0; r < 4; ++r)
                        p4[c][r] = fast_exp2(fmaf(s[c][r], c1, -c2));
            }
            float lsum = 0.f;
#pragma unroll
            for (int c = 0; c < 4; ++c)
                lsum += (p4[c][0] + p4[c][1]) + (p4[c][2] + p4[c][3]);
            ls[ms] += lsum;

            // P -> bf16 B-frags (already in B-operand layout for K16 MFMA)
            s16x4 pf[4];
#pragma unroll
            for (int c = 0; c < 4; ++c) {
                bf16x4 v;
#pragma unroll
                for (int r = 0; r < 4; ++r) v[r] = (bf16_t)p4[c][r];
                pf[c] = __builtin_bit_cast(s16x4, v);
            }

            // O^T += V^T . P   (16x16x16, K=16 per key-chunk c)
#pragma unroll
            for (int dc = 0; dc < 4; ++dc)
#pragma unroll
                for (int c = 0; c < 4; ++c)
                    o[ms][dc] = __builtin_amdgcn_mfma_f32_16x16x16bf16_1k(
                        vf[dc][c], pf[c], o[ms][dc], 0, 0, 0);
        }

        __syncthreads();
    }

    // epilogue: reduce row-sum over lq groups, normalize if finalizing,
    // transpose O^T -> row-major via LDS scratch (reuse sK), coalesced stores.
    __syncthreads();                       // all waves done with sK/sVt reads
    bf16_t* sT = &sK[0][0];                // [wave][16 q][72] scratch
    const int b = bh >> 4;
    const int h = bh & 15;
#pragma unroll
    for (int ms = 0; ms < 2; ++ms) {
        float l = ls[ms];
        l += __shfl_xor(l, 16);
        l += __shfl_xor(l, 32);
        const float inv = fin ? (1.0f / l) : 1.0f;
        if (!fin && lq == 0) {             // lanes 0..15 write this ms's l
            const int q = q_base + wv * 32 + ms * 16 + lm;
            float* lb = chunk1 ? l1buf : l0buf;
            lb[bh * 1024 + (q - 1024)] = l;
        }
#pragma unroll
        for (int dc = 0; dc < 4; ++dc)
#pragma unroll
            for (int r = 0; r < 4; ++r)
                sT[wv * 1152 + lm * 72 + dc * 16 + lq * 4 + r] =
                    (bf16_t)(o[ms][dc][r] * inv);
        // within-wave transpose readback: lane -> (q = lane&15, d-half = lane>>4)
        const int t = q_base + wv * 32 + ms * 16 + (lane & 15);
        const bf16_t* src = &sT[wv * 1152 + (lane & 15) * 72 + (lane >> 4) * 16];
        bf16x8 y0 = load8(src);
        bf16x8 y1 = load8(src + 8);
        bf16_t* dst;
        if (chunk1)
            dst = p1 + ((size_t)(bh * 1024 + (t - 1024))) * 64 + (lane >> 4) * 16;
        else
            dst = ybuf + ((size_t)(b * SEQ + t)) * DM + h * DH + (lane >> 4) * 16;
        *reinterpret_cast<bf16x8*>(dst)     = y0;
        *reinterpret_cast<bf16x8*>(dst + 8) = y1;
    }
}

// ---------------------------------------------------------------------------
// post: blocks [0,1024): combine q>=1024 rows: y = (O0+O1)/(l0+l1);
//       blocks [1024,1280): tcvt tiles of w_out -> woutT (16 x 16 tiles).
// ---------------------------------------------------------------------------
__global__ __launch_bounds__(256) void post_kernel(
    bf16_t* __restrict__ yb, const bf16_t* __restrict__ p1,
    const float* __restrict__ l0, const float* __restrict__ l1,
    const float* __restrict__ w_out, bf16_t* __restrict__ woutT)
{
    __shared__ bf16_t tile[64][65];
    const int bid = blockIdx.x;
    if (bid < 1024) {
        const int idx = bid * 256 + threadIdx.x;
        const int d8  = (idx & 7) * 8;
        const int row = idx >> 3;              // bh*1024 + (q-1024)
        const int ql  = row & 1023;
        const int bh  = row >> 10;
        const int q   = 1024 + ql;
        const int b   = bh >> 4, h = bh & 15;
        const float inv = 1.0f / (l0[row] + l1[row]);
        bf16_t* yp = yb + ((size_t)(b * SEQ + q)) * DM + h * DH + d8;
        const bf16_t* pp = p1 + (size_t)row * 64 + d8;
        bf16x8 a = load8(yp), c = load8(pp);
        bf16x8 oo;
#pragma unroll
        for (int j = 0; j < 8; ++j)
            oo[j] = (bf16_t)(((float)a[j] + (float)c[j]) * inv);
        *reinterpret_cast<bf16x8*>(yp) = oo;
    } else {
        const int t = bid - 1024;              // 0..255
        tcvt_tile(w_out, woutT, 1024, (t % 16) * 64, (t / 16) * 64, tile);
    }
}

// ---------------------------------------------------------------------------
extern "C" void kernel_launch(void* const* d_in, const int* in_sizes, int n_in,
                              void* d_out, int out_size, void* d_ws, size_t ws_size,
                              hipStream_t stream)
{
    const float* x     = (const float*)d_in[0];
    const float* w_qkv = (const float*)d_in[1];
    const float* b_qkv = (const float*)d_in[2];
    const float* w_out = (const float*)d_in[3];
    const float* b_out = (const float*)d_in[4];
    float* out = (float*)d_out;

    char* ws = (char*)d_ws;
    bf16_t* qb = (bf16_t*)(ws);                 // 0..8M
    bf16_t* kb = (bf16_t*)(ws + (8u << 20));    // 8..16M
    bf16_t* vb = (bf16_t*)(ws + (16u << 20));   // 16..24M  (VT [B,H,64,T])
    bf16_t* yb = (bf16_t*)(ws + (24u << 20));   // 24..32M
    bf16_t* woutT = qb;   // 2 MB; written after attention (qb dead by then)

    const bool bigws = (ws_size >= ((size_t)38 << 20));

    if (bigws) {
        bf16_t* xb    = yb;                                // dead before attn-Y
        bf16_t* wqkvT = (bf16_t*)(ws + (32u << 20));       // 32..38M (dead after K1)
        pre_kernel<<<dim3(2048 + 768), dim3(256), 0, stream>>>(x, xb, w_qkv, wqkvT);
        gemm_bt_kernel<bf16_t, 0, 128><<<dim3(3072 / 128, 4096 / 128), dim3(256), 0, stream>>>(
            xb, wqkvT, b_qkv, nullptr, qb, kb, vb);

        bf16_t* p1 = (bf16_t*)(ws + (32u << 20));              // 4 MB partials
        float*  l0 = (float*)(ws + (36u << 20));               // 128 KB
        float*  l1 = (float*)(ws + (36u << 20) + (128u << 10));// 128 KB
        attn_kernel<<<dim3(24, BATCH * NH), dim3(256), 0, stream>>>(
            qb, kb, vb, yb, p1, l0, l1, 1);
        post_kernel<<<dim3(1024 + 256), dim3(256), 0, stream>>>(
            yb, p1, l0, l1, w_out, woutT);
    } else {
        bf16_t* wqkvT = yb;
        tcvt_kernel<<<dim3(3072 / 64, 1024 / 64), dim3(256), 0, stream>>>(w_qkv, wqkvT, 3072);
        gemm_bt_kernel<float, 0, 128><<<dim3(3072 / 128, 4096 / 128), dim3(256), 0, stream>>>(
            x, wqkvT, b_qkv, nullptr, qb, kb, vb);
        attn_kernel<<<dim3(16, BATCH * NH), dim3(256), 0, stream>>>(
            qb, kb, vb, yb, yb, nullptr, nullptr, 0);
        tcvt_kernel<<<dim3(1024 / 64, 1024 / 64), dim3(256), 0, stream>>>(w_out, woutT, 1024);
    }

    // K3: output projection, 128x64 tiles (512 blocks, 2/CU) -> d_out fp32
    gemm_bt_kernel<bf16_t, 1, 64><<<dim3(1024 / 64, 4096 / 128), dim3(256), 0, stream>>>(
        yb, woutT, b_out, out, nullptr, nullptr, nullptr);
}

// Round 13
// 223.578 us; speedup vs baseline: 1.0973x; 1.0421x over previous
//
#include <hip/hip_runtime.h>
#include <hip/hip_bf16.h>
#include <stdint.h>

// MHSA: B=2, T=2048, C=1024, H=16, d=64. fp32 in/out, bf16 MFMA, fp32 accum.
// Round 13: attn pair-staging — 128 keys staged per barrier (two 64-key
// sub-tiles computed between barriers). Rationale: compiler emits
// s_waitcnt vmcnt(0) before every s_barrier (m97 barrier-drain), so the
// 64-key double buffer never pipelines; halving barrier count amortizes the
// drain over 2x compute. Registers unchanged (kf/vf reloaded per sub-tile);
// LDS 32->64 KB (2 blocks/CU; measured occupancy was 11% anyway).
// All else byte-identical to r12 (VT-in-global, XOR swizzle, r9 key-split,
// no chunk-skip, K3 NT=64, merged pre/post).

typedef __bf16 bf16_t;
typedef __bf16 bf16x8 __attribute__((ext_vector_type(8)));
typedef __bf16 bf16x4 __attribute__((ext_vector_type(4)));
typedef short  s16x4  __attribute__((ext_vector_type(4)));
typedef float  f32x4  __attribute__((ext_vector_type(4)));

#define SEQ   2048
#define DM    1024
#define NH    16
#define DH    64
#define BATCH 2

__device__ __forceinline__ bf16x8 load8(const bf16_t* p) {
    return *reinterpret_cast<const bf16x8*>(p);
}
__device__ __forceinline__ f32x4 loadf4(const float* p) {
    return *reinterpret_cast<const f32x4*>(p);
}
// async global->LDS, 16B per lane. LDS dest = wave-uniform base + lane*16.
__device__ __forceinline__ void async16(const bf16_t* g, bf16_t* lds_base) {
    __builtin_amdgcn_global_load_lds(
        (const __attribute__((address_space(1))) void*)g,
        (__attribute__((address_space(3))) void*)lds_base, 16, 0, 0);
}
__device__ __forceinline__ float fast_exp2(float x) {
#if __has_builtin(__builtin_amdgcn_exp2f)
    return __builtin_amdgcn_exp2f(x);
#else
    return __expf(x * 0.69314718056f);
#endif
}
// swizzled 64x64 bf16 LDS tile: logical (row, chunk8) at physical chunk8^(row&7)
__device__ __forceinline__ int swz(int row, int chunk) {
    return row * 64 + ((chunk ^ (row & 7)) * 8);
}

// ---------------------------------------------------------------------------
// tcvt helper (device): transpose+convert one 64x64 tile of w [1024][N] fp32
// into wT [N][1024] bf16.
// ---------------------------------------------------------------------------
__device__ __forceinline__ void tcvt_tile(
    const float* __restrict__ w, bf16_t* __restrict__ wT, int N,
    int n0, int k0, bf16_t (*tile)[65])
{
    const int tid = threadIdx.x;
#pragma unroll
    for (int i = 0; i < 4; ++i) {
        const int r = i * 16 + (tid >> 4);      // k-local
        const int c = (tid & 15) * 4;           // n-local
        f32x4 v = loadf4(w + (size_t)(k0 + r) * N + n0 + c);
#pragma unroll
        for (int j = 0; j < 4; ++j) tile[c + j][r] = (bf16_t)v[j];
    }
    __syncthreads();
#pragma unroll
    for (int i = 0; i < 4; ++i) {
        const int r = i * 16 + (tid >> 4);      // n-local
        const int c = (tid & 15) * 4;           // k-local
        ushort4 v;
        v.x = *(const uint16_t*)&tile[r][c];
        v.y = *(const uint16_t*)&tile[r][c + 1];
        v.z = *(const uint16_t*)&tile[r][c + 2];
        v.w = *(const uint16_t*)&tile[r][c + 3];
        *reinterpret_cast<ushort4*>(wT + (size_t)(n0 + r) * DM + k0 + c) = v;
    }
}

// ---------------------------------------------------------------------------
// pre: blocks [0,2048): x fp32 -> xb bf16 (8 elems/thread);
//      blocks [2048,2816): tcvt tiles of w_qkv (48 x 16 tiles).
// ---------------------------------------------------------------------------
__global__ __launch_bounds__(256) void pre_kernel(
    const float* __restrict__ x, bf16_t* __restrict__ xb,
    const float* __restrict__ w_qkv, bf16_t* __restrict__ wqkvT)
{
    __shared__ bf16_t tile[64][65];
    const int bid = blockIdx.x;
    if (bid < 2048) {
        const int i = (bid * 256 + threadIdx.x) * 8;
        f32x4 a = loadf4(x + i);
        f32x4 b = loadf4(x + i + 4);
        bf16x8 v;
#pragma unroll
        for (int j = 0; j < 4; ++j) { v[j] = (bf16_t)a[j]; v[4 + j] = (bf16_t)b[j]; }
        *reinterpret_cast<bf16x8*>(xb + i) = v;
    } else {
        const int t = bid - 2048;                // 0..767
        tcvt_tile(w_qkv, wqkvT, 3072, (t % 48) * 64, (t / 48) * 64, tile);
    }
}

// standalone tcvt (small-ws path)
__global__ __launch_bounds__(256) void tcvt_kernel(
    const float* __restrict__ w, bf16_t* __restrict__ wT, int N)
{
    __shared__ bf16_t tile[64][65];
    tcvt_tile(w, wT, N, blockIdx.x * 64, blockIdx.y * 64, tile);
}

// ---------------------------------------------------------------------------
// 128xNT-tile bf16 GEMM, K=1024, BK=64. A [M,1024] row-major (TA = float:
// convert-in-staging; TA = bf16: global_load_lds). BT [N,1024] bf16.
// Block 256 = 4 waves (2x2): wave covers 64 x NT/2 (4 x NT/32 MFMA subtiles).
// MODE 0: Q,K scattered to [B,H,T,64]; V scattered TRANSPOSED to [B,H,64,T]
// (8B stores: 4 consecutive t). MODE 1: fp32 out + bias.
// ---------------------------------------------------------------------------
template <typename TA, int MODE, int NT>
__global__ __launch_bounds__(256) void gemm_bt_kernel(
    const TA* __restrict__ A, const bf16_t* __restrict__ BT,
    const float* __restrict__ bias,
    float* __restrict__ outF,
    bf16_t* __restrict__ oq, bf16_t* __restrict__ ok, bf16_t* __restrict__ ov)
{
    constexpr int SAS = (sizeof(TA) == 4) ? 72 : 64;   // sA row stride (elems)
    constexpr int NB  = NT / 32;                       // b-subtiles per wave
    __shared__ bf16_t sA[128 * SAS];
    __shared__ bf16_t sB[NT * 64];

    const int tid  = threadIdx.x;
    const int lane = tid & 63;
    const int wv   = tid >> 6;
    const int lq   = lane >> 4;
    const int lm   = lane & 15;
    const int wm   = (wv >> 1) * 64;
    const int wn   = (wv & 1) * (NT / 2);
    const int mb   = blockIdx.y * 128;
    const int nb   = blockIdx.x * NT;

    const int srow = lane >> 3;          // 0..7
    const int scol = (lane & 7) * 8;     // elem offset (16B chunks)

    f32x4 acc[4][NB];
#pragma unroll
    for (int a = 0; a < 4; ++a)
#pragma unroll
        for (int b = 0; b < NB; ++b) acc[a][b] = f32x4{0.f, 0.f, 0.f, 0.f};

    for (int it = 0; it < 16; ++it) {
        const int k0 = it * 64;
        if constexpr (sizeof(TA) == 4) {
            const int arow = tid >> 1;
            const int akc  = (tid & 1) * 32;
            const float* g = (const float*)A + (size_t)(mb + arow) * DM + k0 + akc;
            bf16_t* dst = &sA[arow * SAS + akc];
#pragma unroll
            for (int j = 0; j < 4; ++j) {
                f32x4 u0 = loadf4(g + j * 8);
                f32x4 u1 = loadf4(g + j * 8 + 4);
                bf16x8 w;
#pragma unroll
                for (int e = 0; e < 4; ++e) { w[e] = (bf16_t)u0[e]; w[4 + e] = (bf16_t)u1[e]; }
                *reinterpret_cast<bf16x8*>(dst + j * 8) = w;
            }
        } else {
#pragma unroll
            for (int r = 0; r < 4; ++r) {
                const int row = wv * 32 + r * 8 + srow;
                async16((const bf16_t*)A + (size_t)(mb + row) * DM + k0 + scol,
                        &sA[wv * 2048 + r * 512]);
            }
        }
#pragma unroll
        for (int r = 0; r < NT / 32; ++r) {
            const int row = wv * (NT / 4) + r * 8 + srow;
            async16(BT + (size_t)(nb + row) * DM + k0 + scol,
                    &sB[wv * (NT / 4) * 64 + r * 512]);
        }
        __syncthreads();
#pragma unroll
        for (int kh = 0; kh < 2; ++kh) {
            bf16x8 af[4], bfr[NB];
#pragma unroll
            for (int a = 0; a < 4; ++a)
                af[a] = load8(&sA[(wm + a * 16 + lm) * SAS + kh * 32 + lq * 8]);
#pragma unroll
            for (int b = 0; b < NB; ++b)
                bfr[b] = load8(&sB[(wn + b * 16 + lm) * 64 + kh * 32 + lq * 8]);
#pragma unroll
            for (int a = 0; a < 4; ++a)
#pragma unroll
                for (int b = 0; b < NB; ++b)
                    acc[a][b] = __builtin_amdgcn_mfma_f32_16x16x32_bf16(
                        af[a], bfr[b], acc[a][b], 0, 0, 0);
        }
        __syncthreads();
    }

    // epilogue: C/D layout col = lane&15, row = (lane>>4)*4 + r
#pragma unroll
    for (int b = 0; b < NB; ++b) {
        const int n = nb + wn + b * 16 + lm;
        const float bv = bias[n];
        if (MODE == 0) {
            const int which = n >> 10;
            const int cc = n & 1023;
            const int h  = cc >> 6;
            const int d  = cc & 63;
            if (which == 2) {
                // V -> VT[b,h,d,t]: 4 consecutive t per acc column, 8B store
#pragma unroll
                for (int a = 0; a < 4; ++a) {
                    const int m0 = mb + wm + a * 16 + lq * 4;
                    const int bb = m0 >> 11;
                    const int t0 = m0 & 2047;
                    bf16x4 w;
#pragma unroll
                    for (int r = 0; r < 4; ++r) w[r] = (bf16_t)(acc[a][b][r] + bv);
                    *reinterpret_cast<bf16x4*>(
                        ov + ((size_t)(bb * NH + h) * DH + d) * SEQ + t0) = w;
                }
            } else {
                bf16_t* dst = (which == 0) ? oq : ok;
#pragma unroll
                for (int a = 0; a < 4; ++a)
#pragma unroll
                    for (int r = 0; r < 4; ++r) {
                        const int m = mb + wm + a * 16 + lq * 4 + r;
                        const int bb = m >> 11;
                        const int t  = m & 2047;
                        dst[((size_t)(bb * NH + h) * SEQ + t) * DH + d] =
                            (bf16_t)(acc[a][b][r] + bv);
                    }
            }
        } else {
#pragma unroll
            for (int a = 0; a < 4; ++a)
#pragma unroll
                for (int r = 0; r < 4; ++r) {
                    const int m = mb + wm + a * 16 + lq * 4 + r;
                    outF[(size_t)m * DM + n] = acc[a][b][r] + bv;
                }
        }
    }
}

// ---------------------------------------------------------------------------
// Flash attention, S^T formulation, 128-row q-tiles, r9 key-split, PAIRED
// staging: 128 keys (2 x 64-key sub-tiles) per barrier. split=0: grid.x=16,
// qi=15-uid, full range. split=1: grid.x=24 (r9 map). All step counts even.
// K and VT staged via async16, double-buffered at pair granularity,
// XOR-swizzled (chunk c at physical c^(row&7)).
// ---------------------------------------------------------------------------
__global__ __launch_bounds__(256) void attn_kernel(
    const bf16_t* __restrict__ qbuf, const bf16_t* __restrict__ kbuf,
    const bf16_t* __restrict__ vtbuf, bf16_t* __restrict__ ybuf,
    bf16_t* __restrict__ p1, float* __restrict__ l0buf,
    float* __restrict__ l1buf, int split)
{
    __shared__ bf16_t sK[2][2 * 64 * 64];    // [buf][sub-tile][key][d], swizzled
    __shared__ bf16_t sVt[2][2 * 64 * 64];   // [buf][sub-tile][d][key], swizzled

    const int tid  = threadIdx.x;
    const int lane = tid & 63;
    const int wv   = tid >> 6;
    const int lq   = lane >> 4;
    const int lm   = lane & 15;
    const int uid  = blockIdx.x;
    const int bh   = blockIdx.y;

    int qi, kt0, ktn, chunk1;
    if (!split)        { qi = 15 - uid;        kt0 = 0;  ktn = 2 * qi + 2;      chunk1 = 0; }
    else if (uid < 9)  { qi = 15 - uid;        kt0 = 0;  ktn = 16;              chunk1 = 0; }
    else if (uid < 17) { qi = 15 - (uid - 9);  kt0 = 16; ktn = 2 * qi + 2 - 16; chunk1 = 1; }
    else               { qi = 6 - (uid - 17);  kt0 = 0;  ktn = 2 * qi + 2;      chunk1 = 0; }
    const bool fin = !split || (!chunk1 && qi < 8);
    const int q_base = qi * 128;
    const int nps = ktn >> 1;                 // pairs (always integral)

    const size_t hb = (size_t)bh * SEQ * DH;
    const bf16_t* Q  = qbuf + hb;
    const bf16_t* K  = kbuf + hb;
    const bf16_t* VT = vtbuf + hb;            // [d][t] rows of length SEQ

    // Q fragments (B-operand of K.Q^T): lane lm = query, k = lq*8+j over d
    bf16x8 qf0[2], qf1[2];
#pragma unroll
    for (int ms = 0; ms < 2; ++ms) {
        const bf16_t* p = Q + (size_t)(q_base + wv * 32 + ms * 16 + lm) * DH + lq * 8;
        qf0[ms] = load8(p);
        qf1[ms] = load8(p + 32);
    }

    f32x4 o[2][4];                     // O^T: [ms][d-subtile], d=lq*4+r, q=lm
    float ls[2];                       // lane-local row-sum (query = lm)
#pragma unroll
    for (int ms = 0; ms < 2; ++ms) {
        ls[ms] = 0.f;
#pragma unroll
        for (int dc = 0; dc < 4; ++dc) o[ms][dc] = f32x4{0.f, 0.f, 0.f, 0.f};
    }

    const int srow = lane >> 3;                    // staging row sub 0..7
    const int scs  = ((lane & 7) ^ srow) * 8;      // swizzled source chunk

    // prologue: stage pair 0 (keys [kt0*64, kt0*64+128))
    {
        const int kb0 = kt0 * 64;
#pragma unroll
        for (int hf = 0; hf < 2; ++hf)
#pragma unroll
            for (int r = 0; r < 2; ++r) {
                async16(K + (size_t)(kb0 + hf * 64 + wv * 16 + r * 8 + srow) * DH + scs,
                        &sK[0][hf * 4096 + wv * 1024 + r * 512]);
                async16(VT + (size_t)(wv * 16 + r * 8 + srow) * SEQ + kb0 + hf * 64 + scs,
                        &sVt[0][hf * 4096 + wv * 1024 + r * 512]);
            }
    }
    __syncthreads();

    const float c1 = 0.125f * 1.44269504f;   // scale * log2(e)
    const float c2 = 10.0f  * 1.44269504f;   // fixed shift * log2(e)

    for (int sp = 0; sp < nps; ++sp) {
        const int cb = sp & 1, nbuf = cb ^ 1;
        if (sp + 1 < nps) {
            const int kb2 = (kt0 + (sp + 1) * 2) * 64;
#pragma unroll
            for (int hf = 0; hf < 2; ++hf)
#pragma unroll
                for (int r = 0; r < 2; ++r) {
                    async16(K + (size_t)(kb2 + hf * 64 + wv * 16 + r * 8 + srow) * DH + scs,
                            &sK[nbuf][hf * 4096 + wv * 1024 + r * 512]);
                    async16(VT + (size_t)(wv * 16 + r * 8 + srow) * SEQ + kb2 + hf * 64 + scs,
                            &sVt[nbuf][hf * 4096 + wv * 1024 + r * 512]);
                }
        }

#pragma unroll
        for (int hf = 0; hf < 2; ++hf) {
            const int kb = (kt0 + sp * 2 + hf) * 64;
            const bf16_t* sKc = &sK[cb][hf * 4096];
            const bf16_t* sVc = &sVt[cb][hf * 4096];

            // K fragments (A-operand): lane lm = key, k over d; swizzled
            bf16x8 kf0[4], kf1[4];
#pragma unroll
            for (int c = 0; c < 4; ++c) {
                kf0[c] = load8(&sKc[swz(c * 16 + lm, lq)]);
                kf1[c] = load8(&sKc[swz(c * 16 + lm, lq + 4)]);
            }
            // V A-frags: A[m=d: dc*16+lm][k=key: c*16+lq*4+j] (b64, swizzled)
            s16x4 vf[4][4];
#pragma unroll
            for (int dc = 0; dc < 4; ++dc)
#pragma unroll
                for (int c = 0; c < 4; ++c)
                    vf[dc][c] = *reinterpret_cast<const s16x4*>(
                        &sVc[swz(dc * 16 + lm, c * 2 + (lq >> 1)) + (lq & 1) * 4]);

#pragma unroll
            for (int ms = 0; ms < 2; ++ms) {
                const int rowlo = wv * 32 + ms * 16;          // block-relative
                if (q_base + rowlo + 15 < kb) continue;       // fully masked

                // S^T: C[m=key: lq*4+r][n=query: lm]
                f32x4 s[4];
#pragma unroll
                for (int c = 0; c < 4; ++c) {
                    f32x4 z = f32x4{0.f, 0.f, 0.f, 0.f};
                    f32x4 t0 = __builtin_amdgcn_mfma_f32_16x16x32_bf16(kf0[c], qf0[ms], z, 0, 0, 0);
                    s[c] = __builtin_amdgcn_mfma_f32_16x16x32_bf16(kf1[c], qf1[ms], t0, 0, 0, 0);
                }

                const int q = q_base + rowlo + lm;    // this lane's query
                float p4[4][4];
                if (kb + 63 > q_base + rowlo) {       // diagonal region
#pragma unroll
                    for (int c = 0; c < 4; ++c)
#pragma unroll
                        for (int r = 0; r < 4; ++r) {
                            const int key = kb + c * 16 + lq * 4 + r;
                            float t = (key <= q) ? fmaf(s[c][r], c1, -c2) : -1e30f;
                            p4[c][r] = fast_exp2(t);
                        }
                } else {
#pragma unroll
                    for (int c = 0; c < 4; ++c)
#pragma unroll
                        for (int r = 0; r < 4; ++r)
                            p4[c][r] = fast_exp2(fmaf(s[c][r], c1, -c2));
                }
                float lsum = 0.f;
#pragma unroll
                for (int c = 0; c < 4; ++c)
                    lsum += (p4[c][0] + p4[c][1]) + (p4[c][2] + p4[c][3]);
                ls[ms] += lsum;

                // P -> bf16 B-frags (already in B-operand layout for K16 MFMA)
                s16x4 pf[4];
#pragma unroll
                for (int c = 0; c < 4; ++c) {
                    bf16x4 v;
#pragma unroll
                    for (int r = 0; r < 4; ++r) v[r] = (bf16_t)p4[c][r];
                    pf[c] = __builtin_bit_cast(s16x4, v);
                }

                // O^T += V^T . P   (16x16x16, K=16 per key-chunk c)
#pragma unroll
                for (int dc = 0; dc < 4; ++dc)
#pragma unroll
                    for (int c = 0; c < 4; ++c)
                        o[ms][dc] = __builtin_amdgcn_mfma_f32_16x16x16bf16_1k(
                            vf[dc][c], pf[c], o[ms][dc], 0, 0, 0);
            }
        }

        __syncthreads();
    }

    // epilogue: reduce row-sum over lq groups, normalize if finalizing,
    // transpose O^T -> row-major via LDS scratch (reuse sK), coalesced stores.
    __syncthreads();                       // all waves done with sK/sVt reads
    bf16_t* sT = &sK[0][0];                // [wave][16 q][72] scratch
    const int b = bh >> 4;
    const int h = bh & 15;
#pragma unroll
    for (int ms = 0; ms < 2; ++ms) {
        float l = ls[ms];
        l += __shfl_xor(l, 16);
        l += __shfl_xor(l, 32);
        const float inv = fin ? (1.0f / l) : 1.0f;
        if (!fin && lq == 0) {             // lanes 0..15 write this ms's l
            const int q = q_base + wv * 32 + ms * 16 + lm;
            float* lb = chunk1 ? l1buf : l0buf;
            lb[bh * 1024 + (q - 1024)] = l;
        }
#pragma unroll
        for (int dc = 0; dc < 4; ++dc)
#pragma unroll
            for (int r = 0; r < 4; ++r)
                sT[wv * 1152 + lm * 72 + dc * 16 + lq * 4 + r] =
                    (bf16_t)(o[ms][dc][r] * inv);
        // within-wave transpose readback: lane -> (q = lane&15, d-half = lane>>4)
        const int t = q_base + wv * 32 + ms * 16 + (lane & 15);
        const bf16_t* src = &sT[wv * 1152 + (lane & 15) * 72 + (lane >> 4) * 16];
        bf16x8 y0 = load8(src);
        bf16x8 y1 = load8(src + 8);
        bf16_t* dst;
        if (chunk1)
            dst = p1 + ((size_t)(bh * 1024 + (t - 1024))) * 64 + (lane >> 4) * 16;
        else
            dst = ybuf + ((size_t)(b * SEQ + t)) * DM + h * DH + (lane >> 4) * 16;
        *reinterpret_cast<bf16x8*>(dst)     = y0;
        *reinterpret_cast<bf16x8*>(dst + 8) = y1;
    }
}

// ---------------------------------------------------------------------------
// post: blocks [0,1024): combine q>=1024 rows: y = (O0+O1)/(l0+l1);
//       blocks [1024,1280): tcvt tiles of w_out -> woutT (16 x 16 tiles).
// ---------------------------------------------------------------------------
__global__ __launch_bounds__(256) void post_kernel(
    bf16_t* __restrict__ yb, const bf16_t* __restrict__ p1,
    const float* __restrict__ l0, const float* __restrict__ l1,
    const float* __restrict__ w_out, bf16_t* __restrict__ woutT)
{
    __shared__ bf16_t tile[64][65];
    const int bid = blockIdx.x;
    if (bid < 1024) {
        const int idx = bid * 256 + threadIdx.x;
        const int d8  = (idx & 7) * 8;
        const int row = idx >> 3;              // bh*1024 + (q-1024)
        const int ql  = row & 1023;
        const int bh  = row >> 10;
        const int q   = 1024 + ql;
        const int b   = bh >> 4, h = bh & 15;
        const float inv = 1.0f / (l0[row] + l1[row]);
        bf16_t* yp = yb + ((size_t)(b * SEQ + q)) * DM + h * DH + d8;
        const bf16_t* pp = p1 + (size_t)row * 64 + d8;
        bf16x8 a = load8(yp), c = load8(pp);
        bf16x8 oo;
#pragma unroll
        for (int j = 0; j < 8; ++j)
            oo[j] = (bf16_t)(((float)a[j] + (float)c[j]) * inv);
        *reinterpret_cast<bf16x8*>(yp) = oo;
    } else {
        const int t = bid - 1024;              // 0..255
        tcvt_tile(w_out, woutT, 1024, (t % 16) * 64, (t / 16) * 64, tile);
    }
}

// ---------------------------------------------------------------------------
extern "C" void kernel_launch(void* const* d_in, const int* in_sizes, int n_in,
                              void* d_out, int out_size, void* d_ws, size_t ws_size,
                              hipStream_t stream)
{
    const float* x     = (const float*)d_in[0];
    const float* w_qkv = (const float*)d_in[1];
    const float* b_qkv = (const float*)d_in[2];
    const float* w_out = (const float*)d_in[3];
    const float* b_out = (const float*)d_in[4];
    float* out = (float*)d_out;

    char* ws = (char*)d_ws;
    bf16_t* qb = (bf16_t*)(ws);                 // 0..8M
    bf16_t* kb = (bf16_t*)(ws + (8u << 20));    // 8..16M
    bf16_t* vb = (bf16_t*)(ws + (16u << 20));   // 16..24M  (VT [B,H,64,T])
    bf16_t* yb = (bf16_t*)(ws + (24u << 20));   // 24..32M
    bf16_t* woutT = qb;   // 2 MB; written after attention (qb dead by then)

    const bool bigws = (ws_size >= ((size_t)38 << 20));

    if (bigws) {
        bf16_t* xb    = yb;                                // dead before attn-Y
        bf16_t* wqkvT = (bf16_t*)(ws + (32u << 20));       // 32..38M (dead after K1)
        pre_kernel<<<dim3(2048 + 768), dim3(256), 0, stream>>>(x, xb, w_qkv, wqkvT);
        gemm_bt_kernel<bf16_t, 0, 128><<<dim3(3072 / 128, 4096 / 128), dim3(256), 0, stream>>>(
            xb, wqkvT, b_qkv, nullptr, qb, kb, vb);

        bf16_t* p1 = (bf16_t*)(ws + (32u << 20));              // 4 MB partials
        float*  l0 = (float*)(ws + (36u << 20));               // 128 KB
        float*  l1 = (float*)(ws + (36u << 20) + (128u << 10));// 128 KB
        attn_kernel<<<dim3(24, BATCH * NH), dim3(256), 0, stream>>>(
            qb, kb, vb, yb, p1, l0, l1, 1);
        post_kernel<<<dim3(1024 + 256), dim3(256), 0, stream>>>(
            yb, p1, l0, l1, w_out, woutT);
    } else {
        bf16_t* wqkvT = yb;
        tcvt_kernel<<<dim3(3072 / 64, 1024 / 64), dim3(256), 0, stream>>>(w_qkv, wqkvT, 3072);
        gemm_bt_kernel<float, 0, 128><<<dim3(3072 / 128, 4096 / 128), dim3(256), 0, stream>>>(
            x, wqkvT, b_qkv, nullptr, qb, kb, vb);
        attn_kernel<<<dim3(16, BATCH * NH), dim3(256), 0, stream>>>(
            qb, kb, vb, yb, yb, nullptr, nullptr, 0);
        tcvt_kernel<<<dim3(1024 / 64, 1024 / 64), dim3(256), 0, stream>>>(w_out, woutT, 1024);
    }

    // K3: output projection, 128x64 tiles (512 blocks, 2/CU) -> d_out fp32
    gemm_bt_kernel<bf16_t, 1, 64><<<dim3(1024 / 64, 4096 / 128), dim3(256), 0, stream>>>(
        yb, woutT, b_out, out, nullptr, nullptr, nullptr);
}

// Round 14
// 211.701 us; speedup vs baseline: 1.1588x; 1.0561x over previous
//
#include <hip/hip_runtime.h>
#include <hip/hip_bf16.h>
#include <stdint.h>

// MHSA: B=2, T=2048, C=1024, H=16, d=64. fp32 in/out, bf16 MFMA, fp32 accum.
// Round 14: XCD-aware swizzle in attn. r13 counters: attn moves 72MB at only
// 1.09 TB/s; FETCH 57.9MB ~ 2.4x unique footprint -> K/VT refetched from HBM
// because one bh's 24 units scatter over all 8 XCD L2s. Remap flat block id
// so bh == (flat%8) class: all units of a bh share one XCD; 4 bh x 512KB =
// 2MB K/V pinned per 4MB L2. Heuristic only (correctness independent of the
// block->XCD mapping). Everything else byte-identical to r13 (pair-staging,
// VT-in-global, XOR swizzle, r9 key-split, K3 NT=64, merged pre/post).

typedef __bf16 bf16_t;
typedef __bf16 bf16x8 __attribute__((ext_vector_type(8)));
typedef __bf16 bf16x4 __attribute__((ext_vector_type(4)));
typedef short  s16x4  __attribute__((ext_vector_type(4)));
typedef float  f32x4  __attribute__((ext_vector_type(4)));

#define SEQ   2048
#define DM    1024
#define NH    16
#define DH    64
#define BATCH 2

__device__ __forceinline__ bf16x8 load8(const bf16_t* p) {
    return *reinterpret_cast<const bf16x8*>(p);
}
__device__ __forceinline__ f32x4 loadf4(const float* p) {
    return *reinterpret_cast<const f32x4*>(p);
}
// async global->LDS, 16B per lane. LDS dest = wave-uniform base + lane*16.
__device__ __forceinline__ void async16(const bf16_t* g, bf16_t* lds_base) {
    __builtin_amdgcn_global_load_lds(
        (const __attribute__((address_space(1))) void*)g,
        (__attribute__((address_space(3))) void*)lds_base, 16, 0, 0);
}
__device__ __forceinline__ float fast_exp2(float x) {
#if __has_builtin(__builtin_amdgcn_exp2f)
    return __builtin_amdgcn_exp2f(x);
#else
    return __expf(x * 0.69314718056f);
#endif
}
// swizzled 64x64 bf16 LDS tile: logical (row, chunk8) at physical chunk8^(row&7)
__device__ __forceinline__ int swz(int row, int chunk) {
    return row * 64 + ((chunk ^ (row & 7)) * 8);
}

// ---------------------------------------------------------------------------
// tcvt helper (device): transpose+convert one 64x64 tile of w [1024][N] fp32
// into wT [N][1024] bf16.
// ---------------------------------------------------------------------------
__device__ __forceinline__ void tcvt_tile(
    const float* __restrict__ w, bf16_t* __restrict__ wT, int N,
    int n0, int k0, bf16_t (*tile)[65])
{
    const int tid = threadIdx.x;
#pragma unroll
    for (int i = 0; i < 4; ++i) {
        const int r = i * 16 + (tid >> 4);      // k-local
        const int c = (tid & 15) * 4;           // n-local
        f32x4 v = loadf4(w + (size_t)(k0 + r) * N + n0 + c);
#pragma unroll
        for (int j = 0; j < 4; ++j) tile[c + j][r] = (bf16_t)v[j];
    }
    __syncthreads();
#pragma unroll
    for (int i = 0; i < 4; ++i) {
        const int r = i * 16 + (tid >> 4);      // n-local
        const int c = (tid & 15) * 4;           // k-local
        ushort4 v;
        v.x = *(const uint16_t*)&tile[r][c];
        v.y = *(const uint16_t*)&tile[r][c + 1];
        v.z = *(const uint16_t*)&tile[r][c + 2];
        v.w = *(const uint16_t*)&tile[r][c + 3];
        *reinterpret_cast<ushort4*>(wT + (size_t)(n0 + r) * DM + k0 + c) = v;
    }
}

// ---------------------------------------------------------------------------
// pre: blocks [0,2048): x fp32 -> xb bf16 (8 elems/thread);
//      blocks [2048,2816): tcvt tiles of w_qkv (48 x 16 tiles).
// ---------------------------------------------------------------------------
__global__ __launch_bounds__(256) void pre_kernel(
    const float* __restrict__ x, bf16_t* __restrict__ xb,
    const float* __restrict__ w_qkv, bf16_t* __restrict__ wqkvT)
{
    __shared__ bf16_t tile[64][65];
    const int bid = blockIdx.x;
    if (bid < 2048) {
        const int i = (bid * 256 + threadIdx.x) * 8;
        f32x4 a = loadf4(x + i);
        f32x4 b = loadf4(x + i + 4);
        bf16x8 v;
#pragma unroll
        for (int j = 0; j < 4; ++j) { v[j] = (bf16_t)a[j]; v[4 + j] = (bf16_t)b[j]; }
        *reinterpret_cast<bf16x8*>(xb + i) = v;
    } else {
        const int t = bid - 2048;                // 0..767
        tcvt_tile(w_qkv, wqkvT, 3072, (t % 48) * 64, (t / 48) * 64, tile);
    }
}

// standalone tcvt (small-ws path)
__global__ __launch_bounds__(256) void tcvt_kernel(
    const float* __restrict__ w, bf16_t* __restrict__ wT, int N)
{
    __shared__ bf16_t tile[64][65];
    tcvt_tile(w, wT, N, blockIdx.x * 64, blockIdx.y * 64, tile);
}

// ---------------------------------------------------------------------------
// 128xNT-tile bf16 GEMM, K=1024, BK=64. A [M,1024] row-major (TA = float:
// convert-in-staging; TA = bf16: global_load_lds). BT [N,1024] bf16.
// Block 256 = 4 waves (2x2): wave covers 64 x NT/2 (4 x NT/32 MFMA subtiles).
// MODE 0: Q,K scattered to [B,H,T,64]; V scattered TRANSPOSED to [B,H,64,T]
// (8B stores: 4 consecutive t). MODE 1: fp32 out + bias.
// ---------------------------------------------------------------------------
template <typename TA, int MODE, int NT>
__global__ __launch_bounds__(256) void gemm_bt_kernel(
    const TA* __restrict__ A, const bf16_t* __restrict__ BT,
    const float* __restrict__ bias,
    float* __restrict__ outF,
    bf16_t* __restrict__ oq, bf16_t* __restrict__ ok, bf16_t* __restrict__ ov)
{
    constexpr int SAS = (sizeof(TA) == 4) ? 72 : 64;   // sA row stride (elems)
    constexpr int NB  = NT / 32;                       // b-subtiles per wave
    __shared__ bf16_t sA[128 * SAS];
    __shared__ bf16_t sB[NT * 64];

    const int tid  = threadIdx.x;
    const int lane = tid & 63;
    const int wv   = tid >> 6;
    const int lq   = lane >> 4;
    const int lm   = lane & 15;
    const int wm   = (wv >> 1) * 64;
    const int wn   = (wv & 1) * (NT / 2);
    const int mb   = blockIdx.y * 128;
    const int nb   = blockIdx.x * NT;

    const int srow = lane >> 3;          // 0..7
    const int scol = (lane & 7) * 8;     // elem offset (16B chunks)

    f32x4 acc[4][NB];
#pragma unroll
    for (int a = 0; a < 4; ++a)
#pragma unroll
        for (int b = 0; b < NB; ++b) acc[a][b] = f32x4{0.f, 0.f, 0.f, 0.f};

    for (int it = 0; it < 16; ++it) {
        const int k0 = it * 64;
        if constexpr (sizeof(TA) == 4) {
            const int arow = tid >> 1;
            const int akc  = (tid & 1) * 32;
            const float* g = (const float*)A + (size_t)(mb + arow) * DM + k0 + akc;
            bf16_t* dst = &sA[arow * SAS + akc];
#pragma unroll
            for (int j = 0; j < 4; ++j) {
                f32x4 u0 = loadf4(g + j * 8);
                f32x4 u1 = loadf4(g + j * 8 + 4);
                bf16x8 w;
#pragma unroll
                for (int e = 0; e < 4; ++e) { w[e] = (bf16_t)u0[e]; w[4 + e] = (bf16_t)u1[e]; }
                *reinterpret_cast<bf16x8*>(dst + j * 8) = w;
            }
        } else {
#pragma unroll
            for (int r = 0; r < 4; ++r) {
                const int row = wv * 32 + r * 8 + srow;
                async16((const bf16_t*)A + (size_t)(mb + row) * DM + k0 + scol,
                        &sA[wv * 2048 + r * 512]);
            }
        }
#pragma unroll
        for (int r = 0; r < NT / 32; ++r) {
            const int row = wv * (NT / 4) + r * 8 + srow;
            async16(BT + (size_t)(nb + row) * DM + k0 + scol,
                    &sB[wv * (NT / 4) * 64 + r * 512]);
        }
        __syncthreads();
#pragma unroll
        for (int kh = 0; kh < 2; ++kh) {
            bf16x8 af[4], bfr[NB];
#pragma unroll
            for (int a = 0; a < 4; ++a)
                af[a] = load8(&sA[(wm + a * 16 + lm) * SAS + kh * 32 + lq * 8]);
#pragma unroll
            for (int b = 0; b < NB; ++b)
                bfr[b] = load8(&sB[(wn + b * 16 + lm) * 64 + kh * 32 + lq * 8]);
#pragma unroll
            for (int a = 0; a < 4; ++a)
#pragma unroll
                for (int b = 0; b < NB; ++b)
                    acc[a][b] = __builtin_amdgcn_mfma_f32_16x16x32_bf16(
                        af[a], bfr[b], acc[a][b], 0, 0, 0);
        }
        __syncthreads();
    }

    // epilogue: C/D layout col = lane&15, row = (lane>>4)*4 + r
#pragma unroll
    for (int b = 0; b < NB; ++b) {
        const int n = nb + wn + b * 16 + lm;
        const float bv = bias[n];
        if (MODE == 0) {
            const int which = n >> 10;
            const int cc = n & 1023;
            const int h  = cc >> 6;
            const int d  = cc & 63;
            if (which == 2) {
                // V -> VT[b,h,d,t]: 4 consecutive t per acc column, 8B store
#pragma unroll
                for (int a = 0; a < 4; ++a) {
                    const int m0 = mb + wm + a * 16 + lq * 4;
                    const int bb = m0 >> 11;
                    const int t0 = m0 & 2047;
                    bf16x4 w;
#pragma unroll
                    for (int r = 0; r < 4; ++r) w[r] = (bf16_t)(acc[a][b][r] + bv);
                    *reinterpret_cast<bf16x4*>(
                        ov + ((size_t)(bb * NH + h) * DH + d) * SEQ + t0) = w;
                }
            } else {
                bf16_t* dst = (which == 0) ? oq : ok;
#pragma unroll
                for (int a = 0; a < 4; ++a)
#pragma unroll
                    for (int r = 0; r < 4; ++r) {
                        const int m = mb + wm + a * 16 + lq * 4 + r;
                        const int bb = m >> 11;
                        const int t  = m & 2047;
                        dst[((size_t)(bb * NH + h) * SEQ + t) * DH + d] =
                            (bf16_t)(acc[a][b][r] + bv);
                    }
            }
        } else {
#pragma unroll
            for (int a = 0; a < 4; ++a)
#pragma unroll
                for (int r = 0; r < 4; ++r) {
                    const int m = mb + wm + a * 16 + lq * 4 + r;
                    outF[(size_t)m * DM + n] = acc[a][b][r] + bv;
                }
        }
    }
}

// ---------------------------------------------------------------------------
// Flash attention, S^T formulation, 128-row q-tiles, r9 key-split, PAIRED
// staging (r13), XCD-aware block swizzle (r14): flat block id p decodes to
// (bh, uid) with bh == p%8 + 8*((p>>3)&3) so every unit of a bh lands on one
// XCD class (p%8 round-robin heuristic); per-XCD L2 then pins 4 bh x 512 KB
// of K/VT. Big units (uid 0) still dispatch first within every class.
// ---------------------------------------------------------------------------
__global__ __launch_bounds__(256) void attn_kernel(
    const bf16_t* __restrict__ qbuf, const bf16_t* __restrict__ kbuf,
    const bf16_t* __restrict__ vtbuf, bf16_t* __restrict__ ybuf,
    bf16_t* __restrict__ p1, float* __restrict__ l0buf,
    float* __restrict__ l1buf, int split)
{
    __shared__ bf16_t sK[2][2 * 64 * 64];    // [buf][sub-tile][key][d], swizzled
    __shared__ bf16_t sVt[2][2 * 64 * 64];   // [buf][sub-tile][d][key], swizzled

    const int tid  = threadIdx.x;
    const int lane = tid & 63;
    const int wv   = tid >> 6;
    const int lq   = lane >> 4;
    const int lm   = lane & 15;

    // XCD-aware decode: p%8 = XCD class; 4 bh per class; uid slow.
    const int p    = blockIdx.y * gridDim.x + blockIdx.x;
    const int slot = p >> 3;
    const int bh   = (p & 7) + ((slot & 3) << 3);
    const int uid  = slot >> 2;

    int qi, kt0, ktn, chunk1;
    if (!split)        { qi = 15 - uid;        kt0 = 0;  ktn = 2 * qi + 2;      chunk1 = 0; }
    else if (uid < 9)  { qi = 15 - uid;        kt0 = 0;  ktn = 16;              chunk1 = 0; }
    else if (uid < 17) { qi = 15 - (uid - 9);  kt0 = 16; ktn = 2 * qi + 2 - 16; chunk1 = 1; }
    else               { qi = 6 - (uid - 17);  kt0 = 0;  ktn = 2 * qi + 2;      chunk1 = 0; }
    const bool fin = !split || (!chunk1 && qi < 8);
    const int q_base = qi * 128;
    const int nps = ktn >> 1;                 // pairs (always integral)

    const size_t hb = (size_t)bh * SEQ * DH;
    const bf16_t* Q  = qbuf + hb;
    const bf16_t* K  = kbuf + hb;
    const bf16_t* VT = vtbuf + hb;            // [d][t] rows of length SEQ

    // Q fragments (B-operand of K.Q^T): lane lm = query, k = lq*8+j over d
    bf16x8 qf0[2], qf1[2];
#pragma unroll
    for (int ms = 0; ms < 2; ++ms) {
        const bf16_t* p_ = Q + (size_t)(q_base + wv * 32 + ms * 16 + lm) * DH + lq * 8;
        qf0[ms] = load8(p_);
        qf1[ms] = load8(p_ + 32);
    }

    f32x4 o[2][4];                     // O^T: [ms][d-subtile], d=lq*4+r, q=lm
    float ls[2];                       // lane-local row-sum (query = lm)
#pragma unroll
    for (int ms = 0; ms < 2; ++ms) {
        ls[ms] = 0.f;
#pragma unroll
        for (int dc = 0; dc < 4; ++dc) o[ms][dc] = f32x4{0.f, 0.f, 0.f, 0.f};
    }

    const int srow = lane >> 3;                    // staging row sub 0..7
    const int scs  = ((lane & 7) ^ srow) * 8;      // swizzled source chunk

    // prologue: stage pair 0 (keys [kt0*64, kt0*64+128))
    {
        const int kb0 = kt0 * 64;
#pragma unroll
        for (int hf = 0; hf < 2; ++hf)
#pragma unroll
            for (int r = 0; r < 2; ++r) {
                async16(K + (size_t)(kb0 + hf * 64 + wv * 16 + r * 8 + srow) * DH + scs,
                        &sK[0][hf * 4096 + wv * 1024 + r * 512]);
                async16(VT + (size_t)(wv * 16 + r * 8 + srow) * SEQ + kb0 + hf * 64 + scs,
                        &sVt[0][hf * 4096 + wv * 1024 + r * 512]);
            }
    }
    __syncthreads();

    const float c1 = 0.125f * 1.44269504f;   // scale * log2(e)
    const float c2 = 10.0f  * 1.44269504f;   // fixed shift * log2(e)

    for (int sp = 0; sp < nps; ++sp) {
        const int cb = sp & 1, nbuf = cb ^ 1;
        if (sp + 1 < nps) {
            const int kb2 = (kt0 + (sp + 1) * 2) * 64;
#pragma unroll
            for (int hf = 0; hf < 2; ++hf)
#pragma unroll
                for (int r = 0; r < 2; ++r) {
                    async16(K + (size_t)(kb2 + hf * 64 + wv * 16 + r * 8 + srow) * DH + scs,
                            &sK[nbuf][hf * 4096 + wv * 1024 + r * 512]);
                    async16(VT + (size_t)(wv * 16 + r * 8 + srow) * SEQ + kb2 + hf * 64 + scs,
                            &sVt[nbuf][hf * 4096 + wv * 1024 + r * 512]);
                }
        }

#pragma unroll
        for (int hf = 0; hf < 2; ++hf) {
            const int kb = (kt0 + sp * 2 + hf) * 64;
            const bf16_t* sKc = &sK[cb][hf * 4096];
            const bf16_t* sVc = &sVt[cb][hf * 4096];

            // K fragments (A-operand): lane lm = key, k over d; swizzled
            bf16x8 kf0[4], kf1[4];
#pragma unroll
            for (int c = 0; c < 4; ++c) {
                kf0[c] = load8(&sKc[swz(c * 16 + lm, lq)]);
                kf1[c] = load8(&sKc[swz(c * 16 + lm, lq + 4)]);
            }
            // V A-frags: A[m=d: dc*16+lm][k=key: c*16+lq*4+j] (b64, swizzled)
            s16x4 vf[4][4];
#pragma unroll
            for (int dc = 0; dc < 4; ++dc)
#pragma unroll
                for (int c = 0; c < 4; ++c)
                    vf[dc][c] = *reinterpret_cast<const s16x4*>(
                        &sVc[swz(dc * 16 + lm, c * 2 + (lq >> 1)) + (lq & 1) * 4]);

#pragma unroll
            for (int ms = 0; ms < 2; ++ms) {
                const int rowlo = wv * 32 + ms * 16;          // block-relative
                if (q_base + rowlo + 15 < kb) continue;       // fully masked

                // S^T: C[m=key: lq*4+r][n=query: lm]
                f32x4 s[4];
#pragma unroll
                for (int c = 0; c < 4; ++c) {
                    f32x4 z = f32x4{0.f, 0.f, 0.f, 0.f};
                    f32x4 t0 = __builtin_amdgcn_mfma_f32_16x16x32_bf16(kf0[c], qf0[ms], z, 0, 0, 0);
                    s[c] = __builtin_amdgcn_mfma_f32_16x16x32_bf16(kf1[c], qf1[ms], t0, 0, 0, 0);
                }

                const int q = q_base + rowlo + lm;    // this lane's query
                float p4[4][4];
                if (kb + 63 > q_base + rowlo) {       // diagonal region
#pragma unroll
                    for (int c = 0; c < 4; ++c)
#pragma unroll
                        for (int r = 0; r < 4; ++r) {
                            const int key = kb + c * 16 + lq * 4 + r;
                            float t = (key <= q) ? fmaf(s[c][r], c1, -c2) : -1e30f;
                            p4[c][r] = fast_exp2(t);
                        }
                } else {
#pragma unroll
                    for (int c = 0; c < 4; ++c)
#pragma unroll
                        for (int r = 0; r < 4; ++r)
                            p4[c][r] = fast_exp2(fmaf(s[c][r], c1, -c2));
                }
                float lsum = 0.f;
#pragma unroll
                for (int c = 0; c < 4; ++c)
                    lsum += (p4[c][0] + p4[c][1]) + (p4[c][2] + p4[c][3]);
                ls[ms] += lsum;

                // P -> bf16 B-frags (already in B-operand layout for K16 MFMA)
                s16x4 pf[4];
#pragma unroll
                for (int c = 0; c < 4; ++c) {
                    bf16x4 v;
#pragma unroll
                    for (int r = 0; r < 4; ++r) v[r] = (bf16_t)p4[c][r];
                    pf[c] = __builtin_bit_cast(s16x4, v);
                }

                // O^T += V^T . P   (16x16x16, K=16 per key-chunk c)
#pragma unroll
                for (int dc = 0; dc < 4; ++dc)
#pragma unroll
                    for (int c = 0; c < 4; ++c)
                        o[ms][dc] = __builtin_amdgcn_mfma_f32_16x16x16bf16_1k(
                            vf[dc][c], pf[c], o[ms][dc], 0, 0, 0);
            }
        }

        __syncthreads();
    }

    // epilogue: reduce row-sum over lq groups, normalize if finalizing,
    // transpose O^T -> row-major via LDS scratch (reuse sK), coalesced stores.
    __syncthreads();                       // all waves done with sK/sVt reads
    bf16_t* sT = &sK[0][0];                // [wave][16 q][72] scratch
    const int b = bh >> 4;
    const int h = bh & 15;
#pragma unroll
    for (int ms = 0; ms < 2; ++ms) {
        float l = ls[ms];
        l += __shfl_xor(l, 16);
        l += __shfl_xor(l, 32);
        const float inv = fin ? (1.0f / l) : 1.0f;
        if (!fin && lq == 0) {             // lanes 0..15 write this ms's l
            const int q = q_base + wv * 32 + ms * 16 + lm;
            float* lb = chunk1 ? l1buf : l0buf;
            lb[bh * 1024 + (q - 1024)] = l;
        }
#pragma unroll
        for (int dc = 0; dc < 4; ++dc)
#pragma unroll
            for (int r = 0; r < 4; ++r)
                sT[wv * 1152 + lm * 72 + dc * 16 + lq * 4 + r] =
                    (bf16_t)(o[ms][dc][r] * inv);
        // within-wave transpose readback: lane -> (q = lane&15, d-half = lane>>4)
        const int t = q_base + wv * 32 + ms * 16 + (lane & 15);
        const bf16_t* src = &sT[wv * 1152 + (lane & 15) * 72 + (lane >> 4) * 16];
        bf16x8 y0 = load8(src);
        bf16x8 y1 = load8(src + 8);
        bf16_t* dst;
        if (chunk1)
            dst = p1 + ((size_t)(bh * 1024 + (t - 1024))) * 64 + (lane >> 4) * 16;
        else
            dst = ybuf + ((size_t)(b * SEQ + t)) * DM + h * DH + (lane >> 4) * 16;
        *reinterpret_cast<bf16x8*>(dst)     = y0;
        *reinterpret_cast<bf16x8*>(dst + 8) = y1;
    }
}

// ---------------------------------------------------------------------------
// post: blocks [0,1024): combine q>=1024 rows: y = (O0+O1)/(l0+l1);
//       blocks [1024,1280): tcvt tiles of w_out -> woutT (16 x 16 tiles).
// ---------------------------------------------------------------------------
__global__ __launch_bounds__(256) void post_kernel(
    bf16_t* __restrict__ yb, const bf16_t* __restrict__ p1,
    const float* __restrict__ l0, const float* __restrict__ l1,
    const float* __restrict__ w_out, bf16_t* __restrict__ woutT)
{
    __shared__ bf16_t tile[64][65];
    const int bid = blockIdx.x;
    if (bid < 1024) {
        const int idx = bid * 256 + threadIdx.x;
        const int d8  = (idx & 7) * 8;
        const int row = idx >> 3;              // bh*1024 + (q-1024)
        const int ql  = row & 1023;
        const int bh  = row >> 10;
        const int q   = 1024 + ql;
        const int b   = bh >> 4, h = bh & 15;
        const float inv = 1.0f / (l0[row] + l1[row]);
        bf16_t* yp = yb + ((size_t)(b * SEQ + q)) * DM + h * DH + d8;
        const bf16_t* pp = p1 + (size_t)row * 64 + d8;
        bf16x8 a = load8(yp), c = load8(pp);
        bf16x8 oo;
#pragma unroll
        for (int j = 0; j < 8; ++j)
            oo[j] = (bf16_t)(((float)a[j] + (float)c[j]) * inv);
        *reinterpret_cast<bf16x8*>(yp) = oo;
    } else {
        const int t = bid - 1024;              // 0..255
        tcvt_tile(w_out, woutT, 1024, (t % 16) * 64, (t / 16) * 64, tile);
    }
}

// ---------------------------------------------------------------------------
extern "C" void kernel_launch(void* const* d_in, const int* in_sizes, int n_in,
                              void* d_out, int out_size, void* d_ws, size_t ws_size,
                              hipStream_t stream)
{
    const float* x     = (const float*)d_in[0];
    const float* w_qkv = (const float*)d_in[1];
    const float* b_qkv = (const float*)d_in[2];
    const float* w_out = (const float*)d_in[3];
    const float* b_out = (const float*)d_in[4];
    float* out = (float*)d_out;

    char* ws = (char*)d_ws;
    bf16_t* qb = (bf16_t*)(ws);                 // 0..8M
    bf16_t* kb = (bf16_t*)(ws + (8u << 20));    // 8..16M
    bf16_t* vb = (bf16_t*)(ws + (16u << 20));   // 16..24M  (VT [B,H,64,T])
    bf16_t* yb = (bf16_t*)(ws + (24u << 20));   // 24..32M
    bf16_t* woutT = qb;   // 2 MB; written after attention (qb dead by then)

    const bool bigws = (ws_size >= ((size_t)38 << 20));

    if (bigws) {
        bf16_t* xb    = yb;                                // dead before attn-Y
        bf16_t* wqkvT = (bf16_t*)(ws + (32u << 20));       // 32..38M (dead after K1)
        pre_kernel<<<dim3(2048 + 768), dim3(256), 0, stream>>>(x, xb, w_qkv, wqkvT);
        gemm_bt_kernel<bf16_t, 0, 128><<<dim3(3072 / 128, 4096 / 128), dim3(256), 0, stream>>>(
            xb, wqkvT, b_qkv, nullptr, qb, kb, vb);

        bf16_t* p1 = (bf16_t*)(ws + (32u << 20));              // 4 MB partials
        float*  l0 = (float*)(ws + (36u << 20));               // 128 KB
        float*  l1 = (float*)(ws + (36u << 20) + (128u << 10));// 128 KB
        attn_kernel<<<dim3(24, BATCH * NH), dim3(256), 0, stream>>>(
            qb, kb, vb, yb, p1, l0, l1, 1);
        post_kernel<<<dim3(1024 + 256), dim3(256), 0, stream>>>(
            yb, p1, l0, l1, w_out, woutT);
    } else {
        bf16_t* wqkvT = yb;
        tcvt_kernel<<<dim3(3072 / 64, 1024 / 64), dim3(256), 0, stream>>>(w_qkv, wqkvT, 3072);
        gemm_bt_kernel<float, 0, 128><<<dim3(3072 / 128, 4096 / 128), dim3(256), 0, stream>>>(
            x, wqkvT, b_qkv, nullptr, qb, kb, vb);
        attn_kernel<<<dim3(16, BATCH * NH), dim3(256), 0, stream>>>(
            qb, kb, vb, yb, yb, nullptr, nullptr, 0);
        tcvt_kernel<<<dim3(1024 / 64, 1024 / 64), dim3(256), 0, stream>>>(w_out, woutT, 1024);
    }

    // K3: output projection, 128x64 tiles (512 blocks, 2/CU) -> d_out fp32
    gemm_bt_kernel<bf16_t, 1, 64><<<dim3(1024 / 64, 4096 / 128), dim3(256), 0, stream>>>(
        yb, woutT, b_out, out, nullptr, nullptr, nullptr);
}

// Round 15
// 186.940 us; speedup vs baseline: 1.3123x; 1.1325x over previous
//
#include <hip/hip_runtime.h>
#include <hip/hip_bf16.h>
#include <stdint.h>

// MHSA: B=2, T=2048, C=1024, H=16, d=64. fp32 in/out, bf16 MFMA, fp32 accum.
// Round 15: GEMM template gets the two attn-verified fixes.
//  (a) XOR swizzle on sA(bf16)/sB staging + fragment reads. Unswizzled row
//      stride 64 elems == 0 mod 32 banks meant every 8-lane ds_read_b128
//      micro-batch hit one 4-bank chunk (~8-way); K1 showed 9.4e6 conflicts
//      and LDS-read cycles (512/blk-iter min) >> MFMA cycles (154).
//  (b) XCD-grouped block decode (flat&7 = class, 4 m-rows per class): A-tiles
//      pinned per-XCD-L2 instead of replicated in 8; in-class neighbors share
//      B-tiles. K1 FETCH was 40 MB vs 14 MB unique; shorter staging drains.
// fp32-A path (small-ws) keeps 72-elem padded linear layout. Attn/pre/post
// byte-identical to r14 (XCD swizzle, pair-staging, VT-in-global, key-split).

typedef __bf16 bf16_t;
typedef __bf16 bf16x8 __attribute__((ext_vector_type(8)));
typedef __bf16 bf16x4 __attribute__((ext_vector_type(4)));
typedef short  s16x4  __attribute__((ext_vector_type(4)));
typedef float  f32x4  __attribute__((ext_vector_type(4)));

#define SEQ   2048
#define DM    1024
#define NH    16
#define DH    64
#define BATCH 2

__device__ __forceinline__ bf16x8 load8(const bf16_t* p) {
    return *reinterpret_cast<const bf16x8*>(p);
}
__device__ __forceinline__ f32x4 loadf4(const float* p) {
    return *reinterpret_cast<const f32x4*>(p);
}
// async global->LDS, 16B per lane. LDS dest = wave-uniform base + lane*16.
__device__ __forceinline__ void async16(const bf16_t* g, bf16_t* lds_base) {
    __builtin_amdgcn_global_load_lds(
        (const __attribute__((address_space(1))) void*)g,
        (__attribute__((address_space(3))) void*)lds_base, 16, 0, 0);
}
__device__ __forceinline__ float fast_exp2(float x) {
#if __has_builtin(__builtin_amdgcn_exp2f)
    return __builtin_amdgcn_exp2f(x);
#else
    return __expf(x * 0.69314718056f);
#endif
}
// swizzled 64x64 bf16 LDS tile: logical (row, chunk8) at physical chunk8^(row&7)
__device__ __forceinline__ int swz(int row, int chunk) {
    return row * 64 + ((chunk ^ (row & 7)) * 8);
}

// ---------------------------------------------------------------------------
// tcvt helper (device): transpose+convert one 64x64 tile of w [1024][N] fp32
// into wT [N][1024] bf16.
// ---------------------------------------------------------------------------
__device__ __forceinline__ void tcvt_tile(
    const float* __restrict__ w, bf16_t* __restrict__ wT, int N,
    int n0, int k0, bf16_t (*tile)[65])
{
    const int tid = threadIdx.x;
#pragma unroll
    for (int i = 0; i < 4; ++i) {
        const int r = i * 16 + (tid >> 4);      // k-local
        const int c = (tid & 15) * 4;           // n-local
        f32x4 v = loadf4(w + (size_t)(k0 + r) * N + n0 + c);
#pragma unroll
        for (int j = 0; j < 4; ++j) tile[c + j][r] = (bf16_t)v[j];
    }
    __syncthreads();
#pragma unroll
    for (int i = 0; i < 4; ++i) {
        const int r = i * 16 + (tid >> 4);      // n-local
        const int c = (tid & 15) * 4;           // k-local
        ushort4 v;
        v.x = *(const uint16_t*)&tile[r][c];
        v.y = *(const uint16_t*)&tile[r][c + 1];
        v.z = *(const uint16_t*)&tile[r][c + 2];
        v.w = *(const uint16_t*)&tile[r][c + 3];
        *reinterpret_cast<ushort4*>(wT + (size_t)(n0 + r) * DM + k0 + c) = v;
    }
}

// ---------------------------------------------------------------------------
// pre: blocks [0,2048): x fp32 -> xb bf16 (8 elems/thread);
//      blocks [2048,2816): tcvt tiles of w_qkv (48 x 16 tiles).
// ---------------------------------------------------------------------------
__global__ __launch_bounds__(256) void pre_kernel(
    const float* __restrict__ x, bf16_t* __restrict__ xb,
    const float* __restrict__ w_qkv, bf16_t* __restrict__ wqkvT)
{
    __shared__ bf16_t tile[64][65];
    const int bid = blockIdx.x;
    if (bid < 2048) {
        const int i = (bid * 256 + threadIdx.x) * 8;
        f32x4 a = loadf4(x + i);
        f32x4 b = loadf4(x + i + 4);
        bf16x8 v;
#pragma unroll
        for (int j = 0; j < 4; ++j) { v[j] = (bf16_t)a[j]; v[4 + j] = (bf16_t)b[j]; }
        *reinterpret_cast<bf16x8*>(xb + i) = v;
    } else {
        const int t = bid - 2048;                // 0..767
        tcvt_tile(w_qkv, wqkvT, 3072, (t % 48) * 64, (t / 48) * 64, tile);
    }
}

// standalone tcvt (small-ws path)
__global__ __launch_bounds__(256) void tcvt_kernel(
    const float* __restrict__ w, bf16_t* __restrict__ wT, int N)
{
    __shared__ bf16_t tile[64][65];
    tcvt_tile(w, wT, N, blockIdx.x * 64, blockIdx.y * 64, tile);
}

// ---------------------------------------------------------------------------
// 128xNT-tile bf16 GEMM, K=1024, BK=64. A [M,1024] row-major (TA = float:
// convert-in-staging, padded linear; TA = bf16: async16 + XOR swizzle).
// BT [N,1024] bf16 (async16 + XOR swizzle). gridDim.y MUST be 32.
// XCD decode: class=flat&7 -> m-rows {class, class+8, class+16, class+24};
// in-class consecutive blocks share a B-tile. Block 256 = 4 waves (2x2).
// MODE 0: Q,K -> [B,H,T,64]; V -> TRANSPOSED [B,H,64,T]. MODE 1: fp32 out.
// ---------------------------------------------------------------------------
template <typename TA, int MODE, int NT>
__global__ __launch_bounds__(256) void gemm_bt_kernel(
    const TA* __restrict__ A, const bf16_t* __restrict__ BT,
    const float* __restrict__ bias,
    float* __restrict__ outF,
    bf16_t* __restrict__ oq, bf16_t* __restrict__ ok, bf16_t* __restrict__ ov)
{
    constexpr int SAS = (sizeof(TA) == 4) ? 72 : 64;   // sA row stride (elems)
    constexpr int NB  = NT / 32;                       // b-subtiles per wave
    __shared__ bf16_t sA[128 * SAS];
    __shared__ bf16_t sB[NT * 64];

    const int tid  = threadIdx.x;
    const int lane = tid & 63;
    const int wv   = tid >> 6;
    const int lq   = lane >> 4;
    const int lm   = lane & 15;
    const int wm   = (wv >> 1) * 64;
    const int wn   = (wv & 1) * (NT / 2);

    // XCD-grouped decode (gridDim.y == 32): class = flat&7 owns 4 m-rows.
    const int flat = blockIdx.y * gridDim.x + blockIdx.x;
    const int cls  = flat & 7;
    const int q8   = flat >> 3;
    const int mb   = (cls + 8 * (q8 & 3)) * 128;
    const int nb   = (q8 >> 2) * NT;

    const int srow = lane >> 3;                    // 0..7
    const int scol = (lane & 7) * 8;               // linear chunk (fp32 path)
    const int scs  = ((lane & 7) ^ srow) * 8;      // swizzled source chunk

    f32x4 acc[4][NB];
#pragma unroll
    for (int a = 0; a < 4; ++a)
#pragma unroll
        for (int b = 0; b < NB; ++b) acc[a][b] = f32x4{0.f, 0.f, 0.f, 0.f};

    for (int it = 0; it < 16; ++it) {
        const int k0 = it * 64;
        if constexpr (sizeof(TA) == 4) {
            // fp32 A: padded linear layout (SAS=72 handles banks)
            const int arow = tid >> 1;
            const int akc  = (tid & 1) * 32;
            const float* g = (const float*)A + (size_t)(mb + arow) * DM + k0 + akc;
            bf16_t* dst = &sA[arow * SAS + akc];
#pragma unroll
            for (int j = 0; j < 4; ++j) {
                f32x4 u0 = loadf4(g + j * 8);
                f32x4 u1 = loadf4(g + j * 8 + 4);
                bf16x8 w;
#pragma unroll
                for (int e = 0; e < 4; ++e) { w[e] = (bf16_t)u0[e]; w[4 + e] = (bf16_t)u1[e]; }
                *reinterpret_cast<bf16x8*>(dst + j * 8) = w;
            }
        } else {
#pragma unroll
            for (int r = 0; r < 4; ++r) {
                const int row = wv * 32 + r * 8 + srow;
                async16((const bf16_t*)A + (size_t)(mb + row) * DM + k0 + scs,
                        &sA[wv * 2048 + r * 512]);
            }
        }
#pragma unroll
        for (int r = 0; r < NT / 32; ++r) {
            const int row = wv * (NT / 4) + r * 8 + srow;
            async16(BT + (size_t)(nb + row) * DM + k0 + scs,
                    &sB[wv * (NT / 4) * 64 + r * 512]);
        }
        __syncthreads();
#pragma unroll
        for (int kh = 0; kh < 2; ++kh) {
            bf16x8 af[4], bfr[NB];
#pragma unroll
            for (int a = 0; a < 4; ++a) {
                if constexpr (sizeof(TA) == 4)
                    af[a] = load8(&sA[(wm + a * 16 + lm) * SAS + kh * 32 + lq * 8]);
                else
                    af[a] = load8(&sA[swz(wm + a * 16 + lm, kh * 4 + lq)]);
            }
#pragma unroll
            for (int b = 0; b < NB; ++b)
                bfr[b] = load8(&sB[swz(wn + b * 16 + lm, kh * 4 + lq)]);
#pragma unroll
            for (int a = 0; a < 4; ++a)
#pragma unroll
                for (int b = 0; b < NB; ++b)
                    acc[a][b] = __builtin_amdgcn_mfma_f32_16x16x32_bf16(
                        af[a], bfr[b], acc[a][b], 0, 0, 0);
        }
        __syncthreads();
    }

    // epilogue: C/D layout col = lane&15, row = (lane>>4)*4 + r
#pragma unroll
    for (int b = 0; b < NB; ++b) {
        const int n = nb + wn + b * 16 + lm;
        const float bv = bias[n];
        if (MODE == 0) {
            const int which = n >> 10;
            const int cc = n & 1023;
            const int h  = cc >> 6;
            const int d  = cc & 63;
            if (which == 2) {
                // V -> VT[b,h,d,t]: 4 consecutive t per acc column, 8B store
#pragma unroll
                for (int a = 0; a < 4; ++a) {
                    const int m0 = mb + wm + a * 16 + lq * 4;
                    const int bb = m0 >> 11;
                    const int t0 = m0 & 2047;
                    bf16x4 w;
#pragma unroll
                    for (int r = 0; r < 4; ++r) w[r] = (bf16_t)(acc[a][b][r] + bv);
                    *reinterpret_cast<bf16x4*>(
                        ov + ((size_t)(bb * NH + h) * DH + d) * SEQ + t0) = w;
                }
            } else {
                bf16_t* dst = (which == 0) ? oq : ok;
#pragma unroll
                for (int a = 0; a < 4; ++a)
#pragma unroll
                    for (int r = 0; r < 4; ++r) {
                        const int m = mb + wm + a * 16 + lq * 4 + r;
                        const int bb = m >> 11;
                        const int t  = m & 2047;
                        dst[((size_t)(bb * NH + h) * SEQ + t) * DH + d] =
                            (bf16_t)(acc[a][b][r] + bv);
                    }
            }
        } else {
#pragma unroll
            for (int a = 0; a < 4; ++a)
#pragma unroll
                for (int r = 0; r < 4; ++r) {
                    const int m = mb + wm + a * 16 + lq * 4 + r;
                    outF[(size_t)m * DM + n] = acc[a][b][r] + bv;
                }
        }
    }
}

// ---------------------------------------------------------------------------
// Flash attention, S^T formulation, 128-row q-tiles, r9 key-split, PAIRED
// staging (r13), XCD-aware block swizzle (r14): flat block id p decodes to
// (bh, uid) with bh == p%8 class so every unit of a bh lands on one XCD;
// per-XCD L2 pins 4 bh x 512 KB of K/VT. Big units dispatch first per class.
// ---------------------------------------------------------------------------
__global__ __launch_bounds__(256) void attn_kernel(
    const bf16_t* __restrict__ qbuf, const bf16_t* __restrict__ kbuf,
    const bf16_t* __restrict__ vtbuf, bf16_t* __restrict__ ybuf,
    bf16_t* __restrict__ p1, float* __restrict__ l0buf,
    float* __restrict__ l1buf, int split)
{
    __shared__ bf16_t sK[2][2 * 64 * 64];    // [buf][sub-tile][key][d], swizzled
    __shared__ bf16_t sVt[2][2 * 64 * 64];   // [buf][sub-tile][d][key], swizzled

    const int tid  = threadIdx.x;
    const int lane = tid & 63;
    const int wv   = tid >> 6;
    const int lq   = lane >> 4;
    const int lm   = lane & 15;

    // XCD-aware decode: p%8 = XCD class; 4 bh per class; uid slow.
    const int p    = blockIdx.y * gridDim.x + blockIdx.x;
    const int slot = p >> 3;
    const int bh   = (p & 7) + ((slot & 3) << 3);
    const int uid  = slot >> 2;

    int qi, kt0, ktn, chunk1;
    if (!split)        { qi = 15 - uid;        kt0 = 0;  ktn = 2 * qi + 2;      chunk1 = 0; }
    else if (uid < 9)  { qi = 15 - uid;        kt0 = 0;  ktn = 16;              chunk1 = 0; }
    else if (uid < 17) { qi = 15 - (uid - 9);  kt0 = 16; ktn = 2 * qi + 2 - 16; chunk1 = 1; }
    else               { qi = 6 - (uid - 17);  kt0 = 0;  ktn = 2 * qi + 2;      chunk1 = 0; }
    const bool fin = !split || (!chunk1 && qi < 8);
    const int q_base = qi * 128;
    const int nps = ktn >> 1;                 // pairs (always integral)

    const size_t hb = (size_t)bh * SEQ * DH;
    const bf16_t* Q  = qbuf + hb;
    const bf16_t* K  = kbuf + hb;
    const bf16_t* VT = vtbuf + hb;            // [d][t] rows of length SEQ

    // Q fragments (B-operand of K.Q^T): lane lm = query, k = lq*8+j over d
    bf16x8 qf0[2], qf1[2];
#pragma unroll
    for (int ms = 0; ms < 2; ++ms) {
        const bf16_t* p_ = Q + (size_t)(q_base + wv * 32 + ms * 16 + lm) * DH + lq * 8;
        qf0[ms] = load8(p_);
        qf1[ms] = load8(p_ + 32);
    }

    f32x4 o[2][4];                     // O^T: [ms][d-subtile], d=lq*4+r, q=lm
    float ls[2];                       // lane-local row-sum (query = lm)
#pragma unroll
    for (int ms = 0; ms < 2; ++ms) {
        ls[ms] = 0.f;
#pragma unroll
        for (int dc = 0; dc < 4; ++dc) o[ms][dc] = f32x4{0.f, 0.f, 0.f, 0.f};
    }

    const int srow = lane >> 3;                    // staging row sub 0..7
    const int scs  = ((lane & 7) ^ srow) * 8;      // swizzled source chunk

    // prologue: stage pair 0 (keys [kt0*64, kt0*64+128))
    {
        const int kb0 = kt0 * 64;
#pragma unroll
        for (int hf = 0; hf < 2; ++hf)
#pragma unroll
            for (int r = 0; r < 2; ++r) {
                async16(K + (size_t)(kb0 + hf * 64 + wv * 16 + r * 8 + srow) * DH + scs,
                        &sK[0][hf * 4096 + wv * 1024 + r * 512]);
                async16(VT + (size_t)(wv * 16 + r * 8 + srow) * SEQ + kb0 + hf * 64 + scs,
                        &sVt[0][hf * 4096 + wv * 1024 + r * 512]);
            }
    }
    __syncthreads();

    const float c1 = 0.125f * 1.44269504f;   // scale * log2(e)
    const float c2 = 10.0f  * 1.44269504f;   // fixed shift * log2(e)

    for (int sp = 0; sp < nps; ++sp) {
        const int cb = sp & 1, nbuf = cb ^ 1;
        if (sp + 1 < nps) {
            const int kb2 = (kt0 + (sp + 1) * 2) * 64;
#pragma unroll
            for (int hf = 0; hf < 2; ++hf)
#pragma unroll
                for (int r = 0; r < 2; ++r) {
                    async16(K + (size_t)(kb2 + hf * 64 + wv * 16 + r * 8 + srow) * DH + scs,
                            &sK[nbuf][hf * 4096 + wv * 1024 + r * 512]);
                    async16(VT + (size_t)(wv * 16 + r * 8 + srow) * SEQ + kb2 + hf * 64 + scs,
                            &sVt[nbuf][hf * 4096 + wv * 1024 + r * 512]);
                }
        }

#pragma unroll
        for (int hf = 0; hf < 2; ++hf) {
            const int kb = (kt0 + sp * 2 + hf) * 64;
            const bf16_t* sKc = &sK[cb][hf * 4096];
            const bf16_t* sVc = &sVt[cb][hf * 4096];

            // K fragments (A-operand): lane lm = key, k over d; swizzled
            bf16x8 kf0[4], kf1[4];
#pragma unroll
            for (int c = 0; c < 4; ++c) {
                kf0[c] = load8(&sKc[swz(c * 16 + lm, lq)]);
                kf1[c] = load8(&sKc[swz(c * 16 + lm, lq + 4)]);
            }
            // V A-frags: A[m=d: dc*16+lm][k=key: c*16+lq*4+j] (b64, swizzled)
            s16x4 vf[4][4];
#pragma unroll
            for (int dc = 0; dc < 4; ++dc)
#pragma unroll
                for (int c = 0; c < 4; ++c)
                    vf[dc][c] = *reinterpret_cast<const s16x4*>(
                        &sVc[swz(dc * 16 + lm, c * 2 + (lq >> 1)) + (lq & 1) * 4]);

#pragma unroll
            for (int ms = 0; ms < 2; ++ms) {
                const int rowlo = wv * 32 + ms * 16;          // block-relative
                if (q_base + rowlo + 15 < kb) continue;       // fully masked

                // S^T: C[m=key: lq*4+r][n=query: lm]
                f32x4 s[4];
#pragma unroll
                for (int c = 0; c < 4; ++c) {
                    f32x4 z = f32x4{0.f, 0.f, 0.f, 0.f};
                    f32x4 t0 = __builtin_amdgcn_mfma_f32_16x16x32_bf16(kf0[c], qf0[ms], z, 0, 0, 0);
                    s[c] = __builtin_amdgcn_mfma_f32_16x16x32_bf16(kf1[c], qf1[ms], t0, 0, 0, 0);
                }

                const int q = q_base + rowlo + lm;    // this lane's query
                float p4[4][4];
                if (kb + 63 > q_base + rowlo) {       // diagonal region
#pragma unroll
                    for (int c = 0; c < 4; ++c)
#pragma unroll
                        for (int r = 0; r < 4; ++r) {
                            const int key = kb + c * 16 + lq * 4 + r;
                            float t = (key <= q) ? fmaf(s[c][r], c1, -c2) : -1e30f;
                            p4[c][r] = fast_exp2(t);
                        }
                } else {
#pragma unroll
                    for (int c = 0; c < 4; ++c)
#pragma unroll
                        for (int r = 0; r < 4; ++r)
                            p4[c][r] = fast_exp2(fmaf(s[c][r], c1, -c2));
                }
                float lsum = 0.f;
#pragma unroll
                for (int c = 0; c < 4; ++c)
                    lsum += (p4[c][0] + p4[c][1]) + (p4[c][2] + p4[c][3]);
                ls[ms] += lsum;

                // P -> bf16 B-frags (already in B-operand layout for K16 MFMA)
                s16x4 pf[4];
#pragma unroll
                for (int c = 0; c < 4; ++c) {
                    bf16x4 v;
#pragma unroll
                    for (int r = 0; r < 4; ++r) v[r] = (bf16_t)p4[c][r];
                    pf[c] = __builtin_bit_cast(s16x4, v);
                }

                // O^T += V^T . P   (16x16x16, K=16 per key-chunk c)
#pragma unroll
                for (int dc = 0; dc < 4; ++dc)
#pragma unroll
                    for (int c = 0; c < 4; ++c)
                        o[ms][dc] = __builtin_amdgcn_mfma_f32_16x16x16bf16_1k(
                            vf[dc][c], pf[c], o[ms][dc], 0, 0, 0);
            }
        }

        __syncthreads();
    }

    // epilogue: reduce row-sum over lq groups, normalize if finalizing,
    // transpose O^T -> row-major via LDS scratch (reuse sK), coalesced stores.
    __syncthreads();                       // all waves done with sK/sVt reads
    bf16_t* sT = &sK[0][0];                // [wave][16 q][72] scratch
    const int b = bh >> 4;
    const int h = bh & 15;
#pragma unroll
    for (int ms = 0; ms < 2; ++ms) {
        float l = ls[ms];
        l += __shfl_xor(l, 16);
        l += __shfl_xor(l, 32);
        const float inv = fin ? (1.0f / l) : 1.0f;
        if (!fin && lq == 0) {             // lanes 0..15 write this ms's l
            const int q = q_base + wv * 32 + ms * 16 + lm;
            float* lb = chunk1 ? l1buf : l0buf;
            lb[bh * 1024 + (q - 1024)] = l;
        }
#pragma unroll
        for (int dc = 0; dc < 4; ++dc)
#pragma unroll
            for (int r = 0; r < 4; ++r)
                sT[wv * 1152 + lm * 72 + dc * 16 + lq * 4 + r] =
                    (bf16_t)(o[ms][dc][r] * inv);
        // within-wave transpose readback: lane -> (q = lane&15, d-half = lane>>4)
        const int t = q_base + wv * 32 + ms * 16 + (lane & 15);
        const bf16_t* src = &sT[wv * 1152 + (lane & 15) * 72 + (lane >> 4) * 16];
        bf16x8 y0 = load8(src);
        bf16x8 y1 = load8(src + 8);
        bf16_t* dst;
        if (chunk1)
            dst = p1 + ((size_t)(bh * 1024 + (t - 1024))) * 64 + (lane >> 4) * 16;
        else
            dst = ybuf + ((size_t)(b * SEQ + t)) * DM + h * DH + (lane >> 4) * 16;
        *reinterpret_cast<bf16x8*>(dst)     = y0;
        *reinterpret_cast<bf16x8*>(dst + 8) = y1;
    }
}

// ---------------------------------------------------------------------------
// post: blocks [0,1024): combine q>=1024 rows: y = (O0+O1)/(l0+l1);
//       blocks [1024,1280): tcvt tiles of w_out -> woutT (16 x 16 tiles).
// ---------------------------------------------------------------------------
__global__ __launch_bounds__(256) void post_kernel(
    bf16_t* __restrict__ yb, const bf16_t* __restrict__ p1,
    const float* __restrict__ l0, const float* __restrict__ l1,
    const float* __restrict__ w_out, bf16_t* __restrict__ woutT)
{
    __shared__ bf16_t tile[64][65];
    const int bid = blockIdx.x;
    if (bid < 1024) {
        const int idx = bid * 256 + threadIdx.x;
        const int d8  = (idx & 7) * 8;
        const int row = idx >> 3;              // bh*1024 + (q-1024)
        const int ql  = row & 1023;
        const int bh  = row >> 10;
        const int q   = 1024 + ql;
        const int b   = bh >> 4, h = bh & 15;
        const float inv = 1.0f / (l0[row] + l1[row]);
        bf16_t* yp = yb + ((size_t)(b * SEQ + q)) * DM + h * DH + d8;
        const bf16_t* pp = p1 + (size_t)row * 64 + d8;
        bf16x8 a = load8(yp), c = load8(pp);
        bf16x8 oo;
#pragma unroll
        for (int j = 0; j < 8; ++j)
            oo[j] = (bf16_t)(((float)a[j] + (float)c[j]) * inv);
        *reinterpret_cast<bf16x8*>(yp) = oo;
    } else {
        const int t = bid - 1024;              // 0..255
        tcvt_tile(w_out, woutT, 1024, (t % 16) * 64, (t / 16) * 64, tile);
    }
}

// ---------------------------------------------------------------------------
extern "C" void kernel_launch(void* const* d_in, const int* in_sizes, int n_in,
                              void* d_out, int out_size, void* d_ws, size_t ws_size,
                              hipStream_t stream)
{
    const float* x     = (const float*)d_in[0];
    const float* w_qkv = (const float*)d_in[1];
    const float* b_qkv = (const float*)d_in[2];
    const float* w_out = (const float*)d_in[3];
    const float* b_out = (const float*)d_in[4];
    float* out = (float*)d_out;

    char* ws = (char*)d_ws;
    bf16_t* qb = (bf16_t*)(ws);                 // 0..8M
    bf16_t* kb = (bf16_t*)(ws + (8u << 20));    // 8..16M
    bf16_t* vb = (bf16_t*)(ws + (16u << 20));   // 16..24M  (VT [B,H,64,T])
    bf16_t* yb = (bf16_t*)(ws + (24u << 20));   // 24..32M
    bf16_t* woutT = qb;   // 2 MB; written after attention (qb dead by then)

    const bool bigws = (ws_size >= ((size_t)38 << 20));

    if (bigws) {
        bf16_t* xb    = yb;                                // dead before attn-Y
        bf16_t* wqkvT = (bf16_t*)(ws + (32u << 20));       // 32..38M (dead after K1)
        pre_kernel<<<dim3(2048 + 768), dim3(256), 0, stream>>>(x, xb, w_qkv, wqkvT);
        gemm_bt_kernel<bf16_t, 0, 128><<<dim3(3072 / 128, 4096 / 128), dim3(256), 0, stream>>>(
            xb, wqkvT, b_qkv, nullptr, qb, kb, vb);

        bf16_t* p1 = (bf16_t*)(ws + (32u << 20));              // 4 MB partials
        float*  l0 = (float*)(ws + (36u << 20));               // 128 KB
        float*  l1 = (float*)(ws + (36u << 20) + (128u << 10));// 128 KB
        attn_kernel<<<dim3(24, BATCH * NH), dim3(256), 0, stream>>>(
            qb, kb, vb, yb, p1, l0, l1, 1);
        post_kernel<<<dim3(1024 + 256), dim3(256), 0, stream>>>(
            yb, p1, l0, l1, w_out, woutT);
    } else {
        bf16_t* wqkvT = yb;
        tcvt_kernel<<<dim3(3072 / 64, 1024 / 64), dim3(256), 0, stream>>>(w_qkv, wqkvT, 3072);
        gemm_bt_kernel<float, 0, 128><<<dim3(3072 / 128, 4096 / 128), dim3(256), 0, stream>>>(
            x, wqkvT, b_qkv, nullptr, qb, kb, vb);
        attn_kernel<<<dim3(16, BATCH * NH), dim3(256), 0, stream>>>(
            qb, kb, vb, yb, yb, nullptr, nullptr, 0);
        tcvt_kernel<<<dim3(1024 / 64, 1024 / 64), dim3(256), 0, stream>>>(w_out, woutT, 1024);
    }

    // K3: output projection, 128x64 tiles (512 blocks, 2/CU) -> d_out fp32
    gemm_bt_kernel<bf16_t, 1, 64><<<dim3(1024 / 64, 4096 / 128), dim3(256), 0, stream>>>(
        yb, woutT, b_out, out, nullptr, nullptr, nullptr);
}